// Round 1
// baseline (2817.428 us; speedup 1.0000x reference)
//
#include <hip/hip_runtime.h>
#include <cstdint>
#include <cstddef>

#define BROWS 32768
#define NEXP 8

typedef short bf16x8 __attribute__((ext_vector_type(8)));
typedef float f32x4 __attribute__((ext_vector_type(4)));

__device__ __forceinline__ unsigned short f2b(float f) {
  union { float f; unsigned u; } v; v.f = f;
  unsigned r = (v.u + 0x7fffu + ((v.u >> 16) & 1u)) >> 16;
  return (unsigned short)r;
}
__device__ __forceinline__ float b2f(unsigned short s) {
  union { unsigned u; float f; } v; v.u = ((unsigned)s) << 16; return v.f;
}

// ---------------- prep kernels ----------------

// f32 [rows, sc] -> bf16 [rows, dc] (zero-pad cols sc..dc)
__global__ void k_convert_pad(const float* __restrict__ src, unsigned short* __restrict__ dst,
                              int rows, int sc, int dc) {
  int i = blockIdx.x * 256 + threadIdx.x;
  if (i >= rows * dc) return;
  int r = i / dc, c = i % dc;
  float v = (c < sc) ? src[(size_t)r * sc + c] : 0.f;
  dst[i] = f2b(v);
}

// src f32 [E][K][N] -> dst bf16 [E][N][Kpad] (transposed per expert, zero-pad K)
__global__ void k_wtrans(const float* __restrict__ src, unsigned short* __restrict__ dst,
                         int K, int N, int Kpad) {
  __shared__ float tile[32][33];
  int e = blockIdx.z;
  int k0 = blockIdx.x * 32, n0 = blockIdx.y * 32;
  int tx = threadIdx.x, ty = threadIdx.y; // 32 x 8
  for (int i = 0; i < 32; i += 8) {
    int k = k0 + ty + i;
    tile[ty + i][tx] = (k < K) ? src[((size_t)e * K + k) * N + n0 + tx] : 0.f;
  }
  __syncthreads();
  for (int i = 0; i < 32; i += 8) {
    int n = n0 + ty + i;
    dst[((size_t)e * N + n) * Kpad + k0 + tx] = f2b(tile[tx][ty + i]);
  }
}

__global__ void k_zero(float* p, int n) {
  int i = blockIdx.x * 64 + threadIdx.x;
  if (i < n) p[i] = 0.f;
}

// ---------------- main expert layer: Out = LN(ELU(A@W + b)) ----------------
// A bf16 [B, KD] (row stride As), Wt bf16 [ND][KD], out bf16 row stride Os at col Ocol.
// Block: 512 thr = 8 waves (2 M x 4 N). Block tile 64 x ND (full row -> fused LN).
template<int KD, int ND>
__launch_bounds__(512, 4)
__global__ void k_layer(const unsigned short* __restrict__ A, int As,
                        const unsigned short* __restrict__ Wt,
                        const float* __restrict__ bias,
                        const float* __restrict__ gamma,
                        const float* __restrict__ beta,
                        unsigned short* __restrict__ Out, int Os, int Ocol) {
  constexpr int WC = ND / 4;   // cols per wave
  constexpr int NF = WC / 16;  // 16-wide n-frags per wave
  constexpr int NK = KD / 64;  // K tiles
  static_assert(NF >= 1 && KD % 64 == 0, "shape");

  __shared__ unsigned short smem[2][64 * 64]; // A tiles, swizzled
  __shared__ float red[64][4][2];             // LN partials per row per wn

  int tid = threadIdx.x;
  int lane = tid & 63, wid = tid >> 6;
  int wm = wid >> 2, wn = wid & 3;
  int rb = blockIdx.x * 64;

  // staging: 512 thr x 16B = 8KB = 64 rows x 128B
  int srow = tid >> 3, schunk = tid & 7;
  const unsigned short* aptr = A + (size_t)(rb + srow) * As + schunk * 8;
  int lws = srow * 64 + ((schunk ^ (srow & 7)) << 3);

  f32x4 acc[2][NF] = {};

  {
    uint4 v = *(const uint4*)(aptr);
    *(uint4*)(&smem[0][lws]) = v;
  }
  __syncthreads();

  int l15 = lane & 15, g = lane >> 4;
  for (int kt = 0; kt < NK; ++kt) {
    int buf = kt & 1;
    if (kt + 1 < NK) {
      uint4 v = *(const uint4*)(aptr + (kt + 1) * 64);
      *(uint4*)(&smem[buf ^ 1][lws]) = v;
    }
#pragma unroll
    for (int kk = 0; kk < 2; ++kk) {
      bf16x8 a[2];
#pragma unroll
      for (int mf = 0; mf < 2; ++mf) {
        int row = wm * 32 + mf * 16 + l15;
        int chunk = (kk * 4 + g) ^ (row & 7);
        a[mf] = *(const bf16x8*)(&smem[buf][row * 64 + chunk * 8]);
      }
#pragma unroll
      for (int nf = 0; nf < NF; ++nf) {
        int n = wn * WC + nf * 16 + l15;
        bf16x8 b = *(const bf16x8*)(Wt + (size_t)n * KD + kt * 64 + kk * 32 + g * 8);
        acc[0][nf] = __builtin_amdgcn_mfma_f32_16x16x32_bf16(a[0], b, acc[0][nf], 0, 0, 0);
        acc[1][nf] = __builtin_amdgcn_mfma_f32_16x16x32_bf16(a[1], b, acc[1][nf], 0, 0, 0);
      }
    }
    __syncthreads();
  }

  // epilogue: bias + ELU, then fused LN over ND, write bf16
  float bia[NF], gam[NF], bet[NF];
#pragma unroll
  for (int nf = 0; nf < NF; ++nf) {
    int n = wn * WC + nf * 16 + l15;
    bia[nf] = bias[n]; gam[nf] = gamma[n]; bet[nf] = beta[n];
  }
#pragma unroll
  for (int mf = 0; mf < 2; ++mf)
#pragma unroll
    for (int nf = 0; nf < NF; ++nf)
#pragma unroll
      for (int r = 0; r < 4; ++r) {
        float x = acc[mf][nf][r] + bia[nf];
        x = (x > 0.f) ? x : expm1f(x);
        acc[mf][nf][r] = x;
      }
  // per-row partial sums over this wave's cols; butterfly across the 16 col-lanes
#pragma unroll
  for (int mf = 0; mf < 2; ++mf)
#pragma unroll
    for (int r = 0; r < 4; ++r) {
      float s1 = 0.f, s2 = 0.f;
#pragma unroll
      for (int nf = 0; nf < NF; ++nf) {
        float x = acc[mf][nf][r];
        s1 += x; s2 += x * x;
      }
#pragma unroll
      for (int m = 1; m <= 8; m <<= 1) {
        s1 += __shfl_xor(s1, m, 64);
        s2 += __shfl_xor(s2, m, 64);
      }
      if (l15 == 0) {
        int row = wm * 32 + mf * 16 + g * 4 + r;
        red[row][wn][0] = s1;
        red[row][wn][1] = s2;
      }
    }
  __syncthreads();
  const float invn = 1.f / (float)ND;
#pragma unroll
  for (int mf = 0; mf < 2; ++mf)
#pragma unroll
    for (int r = 0; r < 4; ++r) {
      int row = wm * 32 + mf * 16 + g * 4 + r;
      float s1 = red[row][0][0] + red[row][1][0] + red[row][2][0] + red[row][3][0];
      float s2 = red[row][0][1] + red[row][1][1] + red[row][2][1] + red[row][3][1];
      float mean = s1 * invn;
      float var = s2 * invn - mean * mean;
      float rstd = rsqrtf(var + 1e-5f);
      size_t orow = (size_t)(rb + row) * Os + Ocol;
#pragma unroll
      for (int nf = 0; nf < NF; ++nf) {
        float y = (acc[mf][nf][r] - mean) * rstd * gam[nf] + bet[nf];
        Out[orow + wn * WC + nf * 16 + l15] = f2b(y);
      }
    }
}

// ---------------- gate fp32 GEMM + ELU ----------------
// Out[B,N] = ELU(A @ W + bias). A optionally split in K (concat of two sources).
template<bool TWOSRC>
__global__ void k_gate(const float* __restrict__ A0, int As0,
                       const float* __restrict__ A1, int As1, int Ksplit,
                       const float* __restrict__ W, const float* __restrict__ bias,
                       int K, int N, float* __restrict__ Out) {
  __shared__ float Asub[16][65];
  __shared__ float Bsub[16][65];
  int tid = threadIdx.x; // 256
  int rb = blockIdx.x * 64, nb = blockIdx.y * 64;
  int tx = tid & 15, ty = tid >> 4;
  float acc[4][4] = {};
  for (int k0 = 0; k0 < K; k0 += 16) {
    {
      int c = tid & 15, r0 = tid >> 4;
#pragma unroll
      for (int p = 0; p < 4; ++p) {
        int r = r0 + p * 16;
        int k = k0 + c;
        float v;
        if (!TWOSRC || k < Ksplit) v = A0[(size_t)(rb + r) * As0 + k];
        else v = A1[(size_t)(rb + r) * As1 + (k - Ksplit)];
        Asub[c][r] = v;
      }
      int cc = tid & 63, kr = tid >> 6;
#pragma unroll
      for (int p = 0; p < 4; ++p) {
        int k = k0 + kr + p * 4;
        Bsub[kr + p * 4][cc] = W[(size_t)k * N + nb + cc];
      }
    }
    __syncthreads();
#pragma unroll
    for (int kk = 0; kk < 16; ++kk) {
      float a[4], b[4];
#pragma unroll
      for (int i = 0; i < 4; ++i) a[i] = Asub[kk][ty * 4 + i];
#pragma unroll
      for (int j = 0; j < 4; ++j) b[j] = Bsub[kk][tx * 4 + j];
#pragma unroll
      for (int i = 0; i < 4; ++i)
#pragma unroll
        for (int j = 0; j < 4; ++j) acc[i][j] += a[i] * b[j];
    }
    __syncthreads();
  }
#pragma unroll
  for (int i = 0; i < 4; ++i)
#pragma unroll
    for (int j = 0; j < 4; ++j) {
      float x = acc[i][j] + bias[nb + tx * 4 + j];
      x = (x > 0.f) ? x : expm1f(x);
      Out[(size_t)(rb + ty * 4 + i) * N + nb + tx * 4 + j] = x;
    }
}

// ---------------- final expert layer 256 -> 12 (no act/LN) ----------------
__global__ void k_out12(const unsigned short* __restrict__ f2buf,
                        const float* __restrict__ fw3, const float* __restrict__ fb3,
                        float* __restrict__ allout, int e) {
  __shared__ unsigned short rowbuf[8 * 256];
  int tid = threadIdx.x; // 128
  int rb = blockIdx.x * 8;
#pragma unroll
  for (int p = 0; p < 2; ++p) {
    int idx = tid + p * 128;           // 256 chunks of 8 elems
    int row = idx >> 5, col = (idx & 31) * 8;
    *(uint4*)(&rowbuf[row * 256 + col]) =
        *(const uint4*)(f2buf + (size_t)(rb + row) * 256 + col);
  }
  __syncthreads();
  int r = tid >> 4, j = tid & 15;
  if (j < 12) {
    float acc = fb3[e * 12 + j];
    for (int k = 0; k < 256; ++k)
      acc += b2f(rowbuf[r * 256 + k]) * fw3[((size_t)e * 256 + k) * 12 + j];
    allout[((size_t)(rb + r) * 8 + e) * 12 + j] = acc;
  }
}

// ---------------- finalize: gate logits, softmax, top2, mix, aux ----------------
#define ACTION_SZ (32768 * 12)
#define AUX_OFF   ACTION_SZ
#define IDX_OFF   (ACTION_SZ + 1)
#define SCO_OFF   (ACTION_SZ + 1 + 32768 * 2)

__global__ void k_finalize(const float* __restrict__ gh2,
                           const float* __restrict__ gw3, const float* __restrict__ gb3,
                           const float* __restrict__ allout,
                           float* __restrict__ out, float* __restrict__ aux) {
  int b = blockIdx.x * 256 + threadIdx.x;
  __shared__ float sc[8], sp[8];
  if (threadIdx.x < 8) { sc[threadIdx.x] = 0.f; sp[threadIdx.x] = 0.f; }
  __syncthreads();
  float probs[8];
  int i0 = 0, i1 = 0;
  bool valid = (b < BROWS);
  if (valid) {
    float lg[8];
#pragma unroll
    for (int j = 0; j < 8; ++j) lg[j] = gb3[j];
    for (int k = 0; k < 128; ++k) {
      float h = gh2[(size_t)b * 128 + k];
#pragma unroll
      for (int j = 0; j < 8; ++j) lg[j] += h * gw3[k * 8 + j];
    }
    float m = lg[0];
#pragma unroll
    for (int j = 1; j < 8; ++j) m = fmaxf(m, lg[j]);
    float sum = 0.f;
#pragma unroll
    for (int j = 0; j < 8; ++j) { float p = expf(lg[j] - m); probs[j] = p; sum += p; }
    float inv = 1.f / sum;
#pragma unroll
    for (int j = 0; j < 8; ++j) probs[j] *= inv;
    // top-2, ties -> lowest index (register-only, no dynamic indexing)
    float v0 = -1e30f;
#pragma unroll
    for (int j = 0; j < 8; ++j) if (probs[j] > v0) { v0 = probs[j]; i0 = j; }
    float v1 = -1e30f; i1 = (i0 == 0) ? 1 : 0;
#pragma unroll
    for (int j = 0; j < 8; ++j) if (j != i0 && probs[j] > v1) { v1 = probs[j]; i1 = j; }
    float wsum = v0 + v1 + 1e-9f;
    float w0 = v0 / wsum, w1 = v1 / wsum;
    const float* a0 = allout + ((size_t)b * 8 + i0) * 12;
    const float* a1 = allout + ((size_t)b * 8 + i1) * 12;
#pragma unroll
    for (int j = 0; j < 12; ++j)
      out[(size_t)b * 12 + j] = w0 * a0[j] + w1 * a1[j];
    out[IDX_OFF + (size_t)b * 2 + 0] = (float)i0;
    out[IDX_OFF + (size_t)b * 2 + 1] = (float)i1;
    out[SCO_OFF + (size_t)b * 2 + 0] = v0;
    out[SCO_OFF + (size_t)b * 2 + 1] = v1;
#pragma unroll
    for (int j = 0; j < 8; ++j) atomicAdd(&sp[j], probs[j]);
    atomicAdd(&sc[i0], 1.f);
    atomicAdd(&sc[i1], 1.f);
  }
  __syncthreads();
  if (threadIdx.x < 8) {
    atomicAdd(&aux[threadIdx.x], sc[threadIdx.x]);
    atomicAdd(&aux[8 + threadIdx.x], sp[threadIdx.x]);
  }
}

__global__ void k_auxfinal(const float* __restrict__ aux, float* __restrict__ out) {
  if (threadIdx.x == 0) {
    float s = 0.f;
#pragma unroll
    for (int e = 0; e < 8; ++e) {
      float f = aux[e] / (32768.f * 2.f);
      float P = aux[8 + e] / 32768.f;
      s += f * P;
    }
    out[AUX_OFF] = 8.f * s;
  }
}

// ---------------- host ----------------

extern "C" void kernel_launch(void* const* d_in, const int* in_sizes, int n_in,
                              void* d_out, int out_size, void* d_ws, size_t ws_size,
                              hipStream_t stream) {
  const float* state = (const float*)d_in[0];
  const float* vlm   = (const float*)d_in[1];
  const float* sw1 = (const float*)d_in[2];  const float* sb1 = (const float*)d_in[3];
  const float* sg1 = (const float*)d_in[4];  const float* sh1 = (const float*)d_in[5];
  const float* sw2 = (const float*)d_in[6];  const float* sb2 = (const float*)d_in[7];
  const float* sg2 = (const float*)d_in[8];  const float* sh2 = (const float*)d_in[9];
  const float* vw1 = (const float*)d_in[10]; const float* vb1 = (const float*)d_in[11];
  const float* vg1 = (const float*)d_in[12]; const float* vh1 = (const float*)d_in[13];
  const float* vw2 = (const float*)d_in[14]; const float* vb2 = (const float*)d_in[15];
  const float* vg2 = (const float*)d_in[16]; const float* vh2 = (const float*)d_in[17];
  const float* fw1 = (const float*)d_in[18]; const float* fb1 = (const float*)d_in[19];
  const float* fg1 = (const float*)d_in[20]; const float* fh1 = (const float*)d_in[21];
  const float* fw2 = (const float*)d_in[22]; const float* fb2 = (const float*)d_in[23];
  const float* fg2 = (const float*)d_in[24]; const float* fh2 = (const float*)d_in[25];
  const float* fw3 = (const float*)d_in[26]; const float* fb3 = (const float*)d_in[27];
  const float* gw1 = (const float*)d_in[28]; const float* gb1 = (const float*)d_in[29];
  const float* gw2 = (const float*)d_in[30]; const float* gb2 = (const float*)d_in[31];
  const float* gw3 = (const float*)d_in[32]; const float* gb3 = (const float*)d_in[33];

  char* ws = (char*)d_ws;
  size_t off = 0;
  auto alloc = [&](size_t bytes) -> char* {
    char* p = ws + off;
    off = (off + bytes + 255) & ~(size_t)255;
    return p;
  };
  unsigned short* st_bf  = (unsigned short*)alloc((size_t)BROWS * 128 * 2);
  unsigned short* vl_bf  = (unsigned short*)alloc((size_t)BROWS * 512 * 2);
  unsigned short* h1s    = (unsigned short*)alloc((size_t)BROWS * 256 * 2);
  unsigned short* h1v    = (unsigned short*)alloc((size_t)BROWS * 512 * 2);
  unsigned short* fusedb = (unsigned short*)alloc((size_t)BROWS * 384 * 2);
  unsigned short* f1b    = (unsigned short*)alloc((size_t)BROWS * 512 * 2);
  unsigned short* f2b_   = (unsigned short*)alloc((size_t)BROWS * 256 * 2);
  float* allout = (float*)alloc((size_t)BROWS * 8 * 12 * 4);
  float* gh1    = (float*)alloc((size_t)BROWS * 256 * 4);
  float* gh2    = (float*)alloc((size_t)BROWS * 128 * 4);
  unsigned short* wt_s1 = (unsigned short*)alloc((size_t)8 * 256 * 128 * 2);
  unsigned short* wt_s2 = (unsigned short*)alloc((size_t)8 * 128 * 256 * 2);
  unsigned short* wt_v1 = (unsigned short*)alloc((size_t)8 * 512 * 512 * 2);
  unsigned short* wt_v2 = (unsigned short*)alloc((size_t)8 * 256 * 512 * 2);
  unsigned short* wt_f1 = (unsigned short*)alloc((size_t)8 * 512 * 384 * 2);
  unsigned short* wt_f2 = (unsigned short*)alloc((size_t)8 * 256 * 512 * 2);
  float* aux = (float*)alloc(64 * 4);
  (void)ws_size; (void)in_sizes; (void)n_in; (void)out_size;

  float* outf = (float*)d_out;

  // prep
  k_convert_pad<<<(BROWS * 128 + 255) / 256, 256, 0, stream>>>(state, st_bf, BROWS, 96, 128);
  k_convert_pad<<<(BROWS * 512 + 255) / 256, 256, 0, stream>>>(vlm, vl_bf, BROWS, 512, 512);
  k_wtrans<<<dim3(4, 8, 8),  dim3(32, 8), 0, stream>>>(sw1, wt_s1, 96, 256, 128);
  k_wtrans<<<dim3(8, 4, 8),  dim3(32, 8), 0, stream>>>(sw2, wt_s2, 256, 128, 256);
  k_wtrans<<<dim3(16, 16, 8), dim3(32, 8), 0, stream>>>(vw1, wt_v1, 512, 512, 512);
  k_wtrans<<<dim3(16, 8, 8), dim3(32, 8), 0, stream>>>(vw2, wt_v2, 512, 256, 512);
  k_wtrans<<<dim3(12, 16, 8), dim3(32, 8), 0, stream>>>(fw1, wt_f1, 384, 512, 384);
  k_wtrans<<<dim3(16, 8, 8), dim3(32, 8), 0, stream>>>(fw2, wt_f2, 512, 256, 512);
  k_zero<<<1, 64, 0, stream>>>(aux, 16);

  // gate (fp32 for exact top-k)
  k_gate<true><<<dim3(512, 4), 256, 0, stream>>>(state, 96, vlm, 512, 96, gw1, gb1, 608, 256, gh1);
  k_gate<false><<<dim3(512, 2), 256, 0, stream>>>(gh1, 256, nullptr, 0, 0, gw2, gb2, 256, 128, gh2);

  // experts (sequential; per-expert reuse of intermediate buffers)
  for (int e = 0; e < 8; ++e) {
    k_layer<128, 256><<<512, 512, 0, stream>>>(st_bf, 128, wt_s1 + (size_t)e * 256 * 128,
        sb1 + e * 256, sg1 + e * 256, sh1 + e * 256, h1s, 256, 0);
    k_layer<256, 128><<<512, 512, 0, stream>>>(h1s, 256, wt_s2 + (size_t)e * 128 * 256,
        sb2 + e * 128, sg2 + e * 128, sh2 + e * 128, fusedb, 384, 0);
    k_layer<512, 512><<<512, 512, 0, stream>>>(vl_bf, 512, wt_v1 + (size_t)e * 512 * 512,
        vb1 + e * 512, vg1 + e * 512, vh1 + e * 512, h1v, 512, 0);
    k_layer<512, 256><<<512, 512, 0, stream>>>(h1v, 512, wt_v2 + (size_t)e * 256 * 512,
        vb2 + e * 256, vg2 + e * 256, vh2 + e * 256, fusedb, 384, 128);
    k_layer<384, 512><<<512, 512, 0, stream>>>(fusedb, 384, wt_f1 + (size_t)e * 512 * 384,
        fb1 + e * 512, fg1 + e * 512, fh1 + e * 512, f1b, 512, 0);
    k_layer<512, 256><<<512, 512, 0, stream>>>(f1b, 512, wt_f2 + (size_t)e * 256 * 512,
        fb2 + e * 256, fg2 + e * 256, fh2 + e * 256, f2b_, 256, 0);
    k_out12<<<BROWS / 8, 128, 0, stream>>>(f2b_, fw3, fb3, allout, e);
  }

  k_finalize<<<BROWS / 256, 256, 0, stream>>>(gh2, gw3, gb3, allout, outf, aux);
  k_auxfinal<<<1, 64, 0, stream>>>(aux, outf);
}

// Round 3
// 1310.392 us; speedup vs baseline: 2.1501x; 2.1501x over previous
//
#include <hip/hip_runtime.h>
#include <cstdint>
#include <cstddef>

#define BROWS 32768
#define NEXP 8
#define CAP 10240          // per-expert row capacity (E[count]=8192, std~78)
#define CAPBLK (CAP / 64)

typedef short bf16x8 __attribute__((ext_vector_type(8)));
typedef float f32x4 __attribute__((ext_vector_type(4)));

__device__ __forceinline__ unsigned short f2b(float f) {
  union { float f; unsigned u; } v; v.f = f;
  unsigned r = (v.u + 0x7fffu + ((v.u >> 16) & 1u)) >> 16;
  return (unsigned short)r;
}
__device__ __forceinline__ float b2f(unsigned short s) {
  union { unsigned u; float f; } v; v.u = ((unsigned)s) << 16; return v.f;
}

// ---------------- prep kernels ----------------

__global__ void k_convert_pad(const float* __restrict__ src, unsigned short* __restrict__ dst,
                              int rows, int sc, int dc) {
  int i = blockIdx.x * 256 + threadIdx.x;
  if (i >= rows * dc) return;
  int r = i / dc, c = i % dc;
  float v = (c < sc) ? src[(size_t)r * sc + c] : 0.f;
  dst[i] = f2b(v);
}

// src f32 [E][K][N] -> dst bf16 [E][N][Kpad]
__global__ void k_wtrans(const float* __restrict__ src, unsigned short* __restrict__ dst,
                         int K, int N, int Kpad) {
  __shared__ float tile[32][33];
  int e = blockIdx.z;
  int k0 = blockIdx.x * 32, n0 = blockIdx.y * 32;
  int tx = threadIdx.x, ty = threadIdx.y; // 32 x 8
  for (int i = 0; i < 32; i += 8) {
    int k = k0 + ty + i;
    tile[ty + i][tx] = (k < K) ? src[((size_t)e * K + k) * N + n0 + tx] : 0.f;
  }
  __syncthreads();
  for (int i = 0; i < 32; i += 8) {
    int n = n0 + ty + i;
    dst[((size_t)e * N + n) * Kpad + k0 + tx] = f2b(tile[tx][ty + i]);
  }
}

__global__ void k_zero(int* p, int n) {
  int i = blockIdx.x * 64 + threadIdx.x;
  if (i < n) p[i] = 0;
}

// ---------------- fp32 gate GEMM: Out = ELU(A@W + bias) ----------------
// 128x128 tile, 256 threads, 8x8 per-thread. BK=32. K split at Ks (32-aligned).
template<bool TWOSRC>
__launch_bounds__(256, 2)
__global__ void k_gemm32(const float* __restrict__ A0, int As0,
                         const float* __restrict__ A1, int As1, int Ks,
                         const float* __restrict__ W, const float* __restrict__ bias,
                         int K, int N, float* __restrict__ Out) {
  __shared__ float Asub[128][33];
  __shared__ float Bsub[32][132];
  int tid = threadIdx.x;
  int rb = blockIdx.x * 128, nb = blockIdx.y * 128;
  int tx = tid & 15, ty = tid >> 4;
  float acc[8][8] = {};

  int ar = tid >> 1, akoff = (tid & 1) * 16;
  int bkr = tid >> 3, bc0 = (tid & 7) * 16;

  for (int k0 = 0; k0 < K; k0 += 32) {
#pragma unroll
    for (int i = 0; i < 4; ++i) {
      int k = k0 + akoff + i * 4;
      float4 v;
      if (!TWOSRC || k < Ks)
        v = *(const float4*)(A0 + (size_t)(rb + ar) * As0 + k);
      else
        v = *(const float4*)(A1 + (size_t)(rb + ar) * As1 + (k - Ks));
      Asub[ar][akoff + i * 4 + 0] = v.x;
      Asub[ar][akoff + i * 4 + 1] = v.y;
      Asub[ar][akoff + i * 4 + 2] = v.z;
      Asub[ar][akoff + i * 4 + 3] = v.w;
    }
#pragma unroll
    for (int i = 0; i < 4; ++i) {
      float4 v = *(const float4*)(W + (size_t)(k0 + bkr) * N + nb + bc0 + i * 4);
      *(float4*)(&Bsub[bkr][bc0 + i * 4]) = v;
    }
    __syncthreads();
#pragma unroll 4
    for (int kk = 0; kk < 32; ++kk) {
      float4 b0 = *(const float4*)(&Bsub[kk][tx * 8]);
      float4 b1 = *(const float4*)(&Bsub[kk][tx * 8 + 4]);
      float bv[8] = {b0.x, b0.y, b0.z, b0.w, b1.x, b1.y, b1.z, b1.w};
      float av[8];
#pragma unroll
      for (int i = 0; i < 8; ++i) av[i] = Asub[ty * 8 + i][kk];
#pragma unroll
      for (int i = 0; i < 8; ++i)
#pragma unroll
        for (int j = 0; j < 8; ++j) acc[i][j] += av[i] * bv[j];
    }
    __syncthreads();
  }
#pragma unroll
  for (int i = 0; i < 8; ++i) {
    size_t orow = (size_t)(rb + ty * 8 + i) * N + nb + tx * 8;
#pragma unroll
    for (int j = 0; j < 8; ++j) {
      float x = acc[i][j] + bias[nb + tx * 8 + j];
      x = (x > 0.f) ? x : expm1f(x);
      Out[orow + j] = x;
    }
  }
}

// ------- gate head: logits, softmax, top-2, perm lists, aux accum -------
#define ACTION_SZ (32768 * 12)
#define AUX_OFF   ACTION_SZ
#define IDX_OFF   (ACTION_SZ + 1)
#define SCO_OFF   (ACTION_SZ + 1 + 32768 * 2)

__global__ void k_gatetop(const float* __restrict__ gh2,
                          const float* __restrict__ gw3, const float* __restrict__ gb3,
                          float* __restrict__ out, float* __restrict__ aux,
                          int* __restrict__ cnt, int* __restrict__ perm,
                          float* __restrict__ selbuf) {
  int b = blockIdx.x * 256 + threadIdx.x;
  int lane = threadIdx.x & 63;
  float lg[8];
#pragma unroll
  for (int j = 0; j < 8; ++j) lg[j] = gb3[j];
  for (int k = 0; k < 128; ++k) {
    float h = gh2[(size_t)b * 128 + k];
#pragma unroll
    for (int j = 0; j < 8; ++j) lg[j] += h * gw3[k * 8 + j];
  }
  float m = lg[0];
#pragma unroll
  for (int j = 1; j < 8; ++j) m = fmaxf(m, lg[j]);
  float probs[8], sum = 0.f;
#pragma unroll
  for (int j = 0; j < 8; ++j) { float p = expf(lg[j] - m); probs[j] = p; sum += p; }
  float inv = 1.f / sum;
#pragma unroll
  for (int j = 0; j < 8; ++j) probs[j] *= inv;
  int i0 = 0, i1;
  float v0 = -1e30f;
#pragma unroll
  for (int j = 0; j < 8; ++j) if (probs[j] > v0) { v0 = probs[j]; i0 = j; }
  float v1 = -1e30f; i1 = (i0 == 0) ? 1 : 0;
#pragma unroll
  for (int j = 0; j < 8; ++j) if (j != i0 && probs[j] > v1) { v1 = probs[j]; i1 = j; }
  float wsum = v0 + v1 + 1e-9f;
  float w0 = v0 / wsum, w1 = v1 / wsum;

  out[IDX_OFF + (size_t)b * 2 + 0] = (float)i0;
  out[IDX_OFF + (size_t)b * 2 + 1] = (float)i1;
  out[SCO_OFF + (size_t)b * 2 + 0] = v0;
  out[SCO_OFF + (size_t)b * 2 + 1] = v1;
  selbuf[(size_t)b * 4 + 0] = (float)i0;
  selbuf[(size_t)b * 4 + 1] = (float)i1;
  selbuf[(size_t)b * 4 + 2] = w0;
  selbuf[(size_t)b * 4 + 3] = w1;

  int s0 = atomicAdd(&cnt[i0], 1);
  if (s0 < CAP) perm[i0 * CAP + s0] = b;
  int s1 = atomicAdd(&cnt[i1], 1);
  if (s1 < CAP) perm[i1 * CAP + s1] = b;

#pragma unroll
  for (int j = 0; j < 8; ++j) {
    float p = probs[j];
#pragma unroll
    for (int mk = 1; mk <= 32; mk <<= 1) p += __shfl_xor(p, mk, 64);
    if (lane == 0) atomicAdd(&aux[j], p);
  }
}

__global__ void k_auxfinal(const int* __restrict__ cnt, const float* __restrict__ aux,
                           float* __restrict__ out) {
  if (threadIdx.x == 0) {
    float s = 0.f;
#pragma unroll
    for (int e = 0; e < 8; ++e) {
      float f = (float)cnt[e] / (32768.f * 2.f);
      float P = aux[e] / 32768.f;
      s += f * P;
    }
    out[AUX_OFF] = 8.f * s;
  }
}

// ------- expert layer: Out = LN(ELU(A@W + b)), gathered rows -------
template<int KD, int ND, bool GATHER>
__launch_bounds__(512, 4)
__global__ void k_layer(const unsigned short* __restrict__ A, int As,
                        const int* __restrict__ perm, const int* __restrict__ cnt,
                        const unsigned short* __restrict__ Wt,
                        const float* __restrict__ bias,
                        const float* __restrict__ gamma,
                        const float* __restrict__ beta,
                        unsigned short* __restrict__ Out, int Os, int Ocol) {
  constexpr int WC = ND / 4;
  constexpr int NF = WC / 16;
  constexpr int NK = KD / 64;
  static_assert(NF >= 1 && KD % 64 == 0, "shape");

  int e = blockIdx.y;
  int count = cnt[e]; if (count > CAP) count = CAP;
  int rb = blockIdx.x * 64;
  if (rb >= count) return;

  __shared__ unsigned short smem[2][64 * 64];
  __shared__ float red[64][4][2];

  int tid = threadIdx.x;
  int lane = tid & 63, wid = tid >> 6;
  int wm = wid >> 2, wn = wid & 3;

  const unsigned short* We = Wt + (size_t)e * ND * KD;
  const float* biasv = bias + e * ND;
  const float* gamv = gamma + e * ND;
  const float* betv = beta + e * ND;

  int srow = tid >> 3, schunk = tid & 7;
  int slot = rb + srow;
  size_t arow;
  if (GATHER) {
    int s = slot < count ? slot : count - 1;
    arow = (size_t)perm[e * CAP + s];
  } else {
    arow = (size_t)e * CAP + slot;
  }
  const unsigned short* aptr = A + arow * As + schunk * 8;
  int lws = srow * 64 + ((schunk ^ (srow & 7)) << 3);

  f32x4 acc[2][NF] = {};

  {
    uint4 v = *(const uint4*)(aptr);
    *(uint4*)(&smem[0][lws]) = v;
  }
  __syncthreads();

  int l15 = lane & 15, g = lane >> 4;
  for (int kt = 0; kt < NK; ++kt) {
    int buf = kt & 1;
    if (kt + 1 < NK) {
      uint4 v = *(const uint4*)(aptr + (kt + 1) * 64);
      *(uint4*)(&smem[buf ^ 1][lws]) = v;
    }
#pragma unroll
    for (int kk = 0; kk < 2; ++kk) {
      bf16x8 a[2];
#pragma unroll
      for (int mf = 0; mf < 2; ++mf) {
        int row = wm * 32 + mf * 16 + l15;
        int chunk = (kk * 4 + g) ^ (row & 7);
        a[mf] = *(const bf16x8*)(&smem[buf][row * 64 + chunk * 8]);
      }
#pragma unroll
      for (int nf = 0; nf < NF; ++nf) {
        int n = wn * WC + nf * 16 + l15;
        bf16x8 b = *(const bf16x8*)(We + (size_t)n * KD + kt * 64 + kk * 32 + g * 8);
        acc[0][nf] = __builtin_amdgcn_mfma_f32_16x16x32_bf16(a[0], b, acc[0][nf], 0, 0, 0);
        acc[1][nf] = __builtin_amdgcn_mfma_f32_16x16x32_bf16(a[1], b, acc[1][nf], 0, 0, 0);
      }
    }
    __syncthreads();
  }

  float bia[NF], gam[NF], bet[NF];
#pragma unroll
  for (int nf = 0; nf < NF; ++nf) {
    int n = wn * WC + nf * 16 + l15;
    bia[nf] = biasv[n]; gam[nf] = gamv[n]; bet[nf] = betv[n];
  }
#pragma unroll
  for (int mf = 0; mf < 2; ++mf)
#pragma unroll
    for (int nf = 0; nf < NF; ++nf)
#pragma unroll
      for (int r = 0; r < 4; ++r) {
        float x = acc[mf][nf][r] + bia[nf];
        x = (x > 0.f) ? x : expm1f(x);
        acc[mf][nf][r] = x;
      }
#pragma unroll
  for (int mf = 0; mf < 2; ++mf)
#pragma unroll
    for (int r = 0; r < 4; ++r) {
      float s1 = 0.f, s2 = 0.f;
#pragma unroll
      for (int nf = 0; nf < NF; ++nf) {
        float x = acc[mf][nf][r];
        s1 += x; s2 += x * x;
      }
#pragma unroll
      for (int m = 1; m <= 8; m <<= 1) {
        s1 += __shfl_xor(s1, m, 64);
        s2 += __shfl_xor(s2, m, 64);
      }
      if (l15 == 0) {
        int row = wm * 32 + mf * 16 + g * 4 + r;
        red[row][wn][0] = s1;
        red[row][wn][1] = s2;
      }
    }
  __syncthreads();
  const float invn = 1.f / (float)ND;
#pragma unroll
  for (int mf = 0; mf < 2; ++mf)
#pragma unroll
    for (int r = 0; r < 4; ++r) {
      int row = wm * 32 + mf * 16 + g * 4 + r;
      float s1 = red[row][0][0] + red[row][1][0] + red[row][2][0] + red[row][3][0];
      float s2 = red[row][0][1] + red[row][1][1] + red[row][2][1] + red[row][3][1];
      float mean = s1 * invn;
      float var = s2 * invn - mean * mean;
      float rstd = rsqrtf(var + 1e-5f);
      size_t orow = ((size_t)e * CAP + rb + row) * Os + Ocol;
#pragma unroll
      for (int nf = 0; nf < NF; ++nf) {
        float y = (acc[mf][nf][r] - mean) * rstd * gam[nf] + bet[nf];
        Out[orow + wn * WC + nf * 16 + l15] = f2b(y);
      }
    }
}

// ------- final expert layer 256 -> 12, scatter to allout -------
__global__ void k_out12(const unsigned short* __restrict__ f2buf,
                        const int* __restrict__ perm, const int* __restrict__ cnt,
                        const float* __restrict__ fw3, const float* __restrict__ fb3,
                        float* __restrict__ allout) {
  int e = blockIdx.y;
  int count = cnt[e]; if (count > CAP) count = CAP;
  int rb = blockIdx.x * 16;
  if (rb >= count) return;
  __shared__ unsigned short rowbuf[16 * 256];
  __shared__ float wsh[256 * 12];
  int tid = threadIdx.x; // 256
  {
    int row = tid >> 4, c0 = (tid & 15) * 16;
    const unsigned short* src = f2buf + ((size_t)e * CAP + rb + row) * 256 + c0;
    *(uint4*)(&rowbuf[row * 256 + c0]) = *(const uint4*)(src);
    *(uint4*)(&rowbuf[row * 256 + c0 + 8]) = *(const uint4*)(src + 8);
  }
  for (int i = tid; i < 256 * 12; i += 256) wsh[i] = fw3[(size_t)e * 256 * 12 + i];
  __syncthreads();
  int r = tid >> 4, j = tid & 15;
  int slot = rb + r;
  if (j < 12 && slot < count) {
    float acc = fb3[e * 12 + j];
    for (int k = 0; k < 256; ++k)
      acc += b2f(rowbuf[r * 256 + k]) * wsh[k * 12 + j];
    int arow = perm[e * CAP + slot];
    allout[((size_t)arow * 8 + e) * 12 + j] = acc;
  }
}

// ------- mix: weighted sum of the two selected expert outputs -------
__global__ void k_mix(const float* __restrict__ selbuf, const float* __restrict__ allout,
                      float* __restrict__ out) {
  int b = blockIdx.x * 256 + threadIdx.x;
  int i0 = (int)selbuf[(size_t)b * 4 + 0];
  int i1 = (int)selbuf[(size_t)b * 4 + 1];
  float w0 = selbuf[(size_t)b * 4 + 2];
  float w1 = selbuf[(size_t)b * 4 + 3];
  const float* a0 = allout + ((size_t)b * 8 + i0) * 12;
  const float* a1 = allout + ((size_t)b * 8 + i1) * 12;
#pragma unroll
  for (int j = 0; j < 12; ++j)
    out[(size_t)b * 12 + j] = w0 * a0[j] + w1 * a1[j];
}

// ---------------- host ----------------

extern "C" void kernel_launch(void* const* d_in, const int* in_sizes, int n_in,
                              void* d_out, int out_size, void* d_ws, size_t ws_size,
                              hipStream_t stream) {
  const float* state = (const float*)d_in[0];
  const float* vlm   = (const float*)d_in[1];
  const float* sw1 = (const float*)d_in[2];  const float* sb1 = (const float*)d_in[3];
  const float* sg1 = (const float*)d_in[4];  const float* sh1 = (const float*)d_in[5];
  const float* sw2 = (const float*)d_in[6];  const float* sb2 = (const float*)d_in[7];
  const float* sg2 = (const float*)d_in[8];  const float* sh2 = (const float*)d_in[9];
  const float* vw1 = (const float*)d_in[10]; const float* vb1 = (const float*)d_in[11];
  const float* vg1 = (const float*)d_in[12]; const float* vh1 = (const float*)d_in[13];
  const float* vw2 = (const float*)d_in[14]; const float* vb2 = (const float*)d_in[15];
  const float* vg2 = (const float*)d_in[16]; const float* vh2 = (const float*)d_in[17];
  const float* fw1 = (const float*)d_in[18]; const float* fb1 = (const float*)d_in[19];
  const float* fg1 = (const float*)d_in[20]; const float* fh1 = (const float*)d_in[21];
  const float* fw2 = (const float*)d_in[22]; const float* fb2 = (const float*)d_in[23];
  const float* fg2 = (const float*)d_in[24]; const float* fh2 = (const float*)d_in[25];
  const float* fw3 = (const float*)d_in[26]; const float* fb3 = (const float*)d_in[27];
  const float* gw1 = (const float*)d_in[28]; const float* gb1 = (const float*)d_in[29];
  const float* gw2 = (const float*)d_in[30]; const float* gb2 = (const float*)d_in[31];
  const float* gw3 = (const float*)d_in[32]; const float* gb3 = (const float*)d_in[33];

  // ---- workspace layout with lifetime-based aliasing (~236 MB total) ----
  char* ws = (char*)d_ws;
  size_t off = 0;
  auto alloc = [&](size_t bytes) -> char* {
    char* p = ws + off;
    off = (off + bytes + 255) & ~(size_t)255;
    return p;
  };
  const size_t SZ_bufA = (size_t)NEXP * CAP * 512 * 2;  // 83.9 MB
  const size_t SZ_gh1  = (size_t)BROWS * 256 * 4;       // 33.6 MB
  const size_t SZ_gh2  = (size_t)BROWS * 128 * 4;       // 16.8 MB

  char* regA = alloc(SZ_bufA);
  unsigned short* bufA  = (unsigned short*)regA;              // h1v / f1b (expert phase)
  float* gh1            = (float*)regA;                       // gate phase only
  float* gh2            = (float*)(regA + SZ_gh1);            // gate phase only
  unsigned short* st_bf = (unsigned short*)(regA + SZ_gh1 + SZ_gh2); // dead after s1 (< v1)

  unsigned short* bufF = (unsigned short*)alloc((size_t)NEXP * CAP * 384 * 2); // 62.9 MB
  unsigned short* bufC = (unsigned short*)alloc((size_t)NEXP * CAP * 256 * 2); // 41.9 MB

  char* regV = alloc((size_t)BROWS * 512 * 2);                 // 33.6 MB
  unsigned short* vl_bf = (unsigned short*)regV;               // dead after v1
  float* allout         = (float*)regV;                        // written at out12 (after v1)

  float* selbuf = (float*)alloc((size_t)BROWS * 4 * 4);
  int*   perm   = (int*)alloc((size_t)NEXP * CAP * 4);
  char*  cntaux = alloc(256);  // cnt: 8 ints at +0, aux: 8 floats at +64
  int*   cnt = (int*)cntaux;
  float* aux = (float*)(cntaux + 64);
  unsigned short* wt_s1 = (unsigned short*)alloc((size_t)8 * 256 * 128 * 2);
  unsigned short* wt_s2 = (unsigned short*)alloc((size_t)8 * 128 * 256 * 2);
  unsigned short* wt_v1 = (unsigned short*)alloc((size_t)8 * 512 * 512 * 2);
  unsigned short* wt_v2 = (unsigned short*)alloc((size_t)8 * 256 * 512 * 2);
  unsigned short* wt_f1 = (unsigned short*)alloc((size_t)8 * 512 * 384 * 2);
  unsigned short* wt_f2 = (unsigned short*)alloc((size_t)8 * 256 * 512 * 2);
  (void)ws_size; (void)in_sizes; (void)n_in; (void)out_size;

  float* outf = (float*)d_out;

  // prep
  k_convert_pad<<<(BROWS * 128 + 255) / 256, 256, 0, stream>>>(state, st_bf, BROWS, 96, 128);
  k_convert_pad<<<(BROWS * 512 + 255) / 256, 256, 0, stream>>>(vlm, vl_bf, BROWS, 512, 512);
  k_wtrans<<<dim3(4, 8, 8),   dim3(32, 8), 0, stream>>>(sw1, wt_s1, 96, 256, 128);
  k_wtrans<<<dim3(8, 4, 8),   dim3(32, 8), 0, stream>>>(sw2, wt_s2, 256, 128, 256);
  k_wtrans<<<dim3(16, 16, 8), dim3(32, 8), 0, stream>>>(vw1, wt_v1, 512, 512, 512);
  k_wtrans<<<dim3(16, 8, 8),  dim3(32, 8), 0, stream>>>(vw2, wt_v2, 512, 256, 512);
  k_wtrans<<<dim3(12, 16, 8), dim3(32, 8), 0, stream>>>(fw1, wt_f1, 384, 512, 384);
  k_wtrans<<<dim3(16, 8, 8),  dim3(32, 8), 0, stream>>>(fw2, wt_f2, 512, 256, 512);
  k_zero<<<1, 64, 0, stream>>>((int*)cntaux, 64);

  // gate (fp32 for exact top-k); gh1/gh2 live inside bufA region (pre-expert phase)
  k_gemm32<true><<<dim3(256, 2), 256, 0, stream>>>(state, 96, vlm, 512, 96,
                                                   gw1, gb1, 608, 256, gh1);
  k_gemm32<false><<<dim3(256, 1), 256, 0, stream>>>(gh1, 256, nullptr, 0, 0,
                                                    gw2, gb2, 256, 128, gh2);
  k_gatetop<<<BROWS / 256, 256, 0, stream>>>(gh2, gw3, gb3, outf, aux, cnt, perm, selbuf);
  k_auxfinal<<<1, 64, 0, stream>>>(cnt, aux, outf);

  // experts: s-layers first (st_bf aliases bufA tail; must finish before v1 writes bufA)
  dim3 lg(CAPBLK, NEXP);
  k_layer<128, 256, true><<<lg, 512, 0, stream>>>(st_bf, 128, perm, cnt, wt_s1,
      sb1, sg1, sh1, bufC, 256, 0);
  k_layer<256, 128, false><<<lg, 512, 0, stream>>>(bufC, 256, perm, cnt, wt_s2,
      sb2, sg2, sh2, bufF, 384, 0);
  k_layer<512, 512, true><<<lg, 512, 0, stream>>>(vl_bf, 512, perm, cnt, wt_v1,
      vb1, vg1, vh1, bufA, 512, 0);
  k_layer<512, 256, false><<<lg, 512, 0, stream>>>(bufA, 512, perm, cnt, wt_v2,
      vb2, vg2, vh2, bufF, 384, 128);
  k_layer<384, 512, false><<<lg, 512, 0, stream>>>(bufF, 384, perm, cnt, wt_f1,
      fb1, fg1, fh1, bufA, 512, 0);
  k_layer<512, 256, false><<<lg, 512, 0, stream>>>(bufA, 512, perm, cnt, wt_f2,
      fb2, fg2, fh2, bufC, 256, 0);
  k_out12<<<dim3(CAP / 16, NEXP), 256, 0, stream>>>(bufC, perm, cnt, fw3, fb3, allout);

  k_mix<<<BROWS / 256, 256, 0, stream>>>(selbuf, allout, outf);
}

// Round 4
// 1020.960 us; speedup vs baseline: 2.7596x; 1.2835x over previous
//
#include <hip/hip_runtime.h>
#include <cstdint>
#include <cstddef>

#define BROWS 32768
#define NEXP 8
#define CAP 10240          // per-expert row capacity (E[count]=8192, std~78)
#define CAPBLK (CAP / 64)

typedef short bf16x8 __attribute__((ext_vector_type(8)));
typedef float f32x4 __attribute__((ext_vector_type(4)));

__device__ __forceinline__ unsigned short f2b(float f) {
  union { float f; unsigned u; } v; v.f = f;
  unsigned r = (v.u + 0x7fffu + ((v.u >> 16) & 1u)) >> 16;
  return (unsigned short)r;
}
__device__ __forceinline__ float b2f(unsigned short s) {
  union { unsigned u; float f; } v; v.u = ((unsigned)s) << 16; return v.f;
}

// ---------------- prep kernels ----------------

__global__ void k_convert_pad(const float* __restrict__ src, unsigned short* __restrict__ dst,
                              int rows, int sc, int dc) {
  int i = blockIdx.x * 256 + threadIdx.x;
  if (i >= rows * dc) return;
  int r = i / dc, c = i % dc;
  float v = (c < sc) ? src[(size_t)r * sc + c] : 0.f;
  dst[i] = f2b(v);
}

// src f32 [E][K][N] -> dst bf16 [E][N][Kpad]
__global__ void k_wtrans(const float* __restrict__ src, unsigned short* __restrict__ dst,
                         int K, int N, int Kpad) {
  __shared__ float tile[32][33];
  int e = blockIdx.z;
  int k0 = blockIdx.x * 32, n0 = blockIdx.y * 32;
  int tx = threadIdx.x, ty = threadIdx.y; // 32 x 8
  for (int i = 0; i < 32; i += 8) {
    int k = k0 + ty + i;
    tile[ty + i][tx] = (k < K) ? src[((size_t)e * K + k) * N + n0 + tx] : 0.f;
  }
  __syncthreads();
  for (int i = 0; i < 32; i += 8) {
    int n = n0 + ty + i;
    dst[((size_t)e * N + n) * Kpad + k0 + tx] = f2b(tile[tx][ty + i]);
  }
}

__global__ void k_zero(int* p, int n) {
  int i = blockIdx.x * 64 + threadIdx.x;
  if (i < n) p[i] = 0;
}

// ---------------- fp32 gate GEMM: Out = ELU(A@W + bias) ----------------
template<bool TWOSRC>
__launch_bounds__(256, 2)
__global__ void k_gemm32(const float* __restrict__ A0, int As0,
                         const float* __restrict__ A1, int As1, int Ks,
                         const float* __restrict__ W, const float* __restrict__ bias,
                         int K, int N, float* __restrict__ Out) {
  __shared__ float Asub[128][33];
  __shared__ float Bsub[32][132];
  int tid = threadIdx.x;
  int rb = blockIdx.x * 128, nb = blockIdx.y * 128;
  int tx = tid & 15, ty = tid >> 4;
  float acc[8][8] = {};

  int ar = tid >> 1, akoff = (tid & 1) * 16;
  int bkr = tid >> 3, bc0 = (tid & 7) * 16;

  for (int k0 = 0; k0 < K; k0 += 32) {
#pragma unroll
    for (int i = 0; i < 4; ++i) {
      int k = k0 + akoff + i * 4;
      float4 v;
      if (!TWOSRC || k < Ks)
        v = *(const float4*)(A0 + (size_t)(rb + ar) * As0 + k);
      else
        v = *(const float4*)(A1 + (size_t)(rb + ar) * As1 + (k - Ks));
      Asub[ar][akoff + i * 4 + 0] = v.x;
      Asub[ar][akoff + i * 4 + 1] = v.y;
      Asub[ar][akoff + i * 4 + 2] = v.z;
      Asub[ar][akoff + i * 4 + 3] = v.w;
    }
#pragma unroll
    for (int i = 0; i < 4; ++i) {
      float4 v = *(const float4*)(W + (size_t)(k0 + bkr) * N + nb + bc0 + i * 4);
      *(float4*)(&Bsub[bkr][bc0 + i * 4]) = v;
    }
    __syncthreads();
#pragma unroll 4
    for (int kk = 0; kk < 32; ++kk) {
      float4 b0 = *(const float4*)(&Bsub[kk][tx * 8]);
      float4 b1 = *(const float4*)(&Bsub[kk][tx * 8 + 4]);
      float bv[8] = {b0.x, b0.y, b0.z, b0.w, b1.x, b1.y, b1.z, b1.w};
      float av[8];
#pragma unroll
      for (int i = 0; i < 8; ++i) av[i] = Asub[ty * 8 + i][kk];
#pragma unroll
      for (int i = 0; i < 8; ++i)
#pragma unroll
        for (int j = 0; j < 8; ++j) acc[i][j] += av[i] * bv[j];
    }
    __syncthreads();
  }
#pragma unroll
  for (int i = 0; i < 8; ++i) {
    size_t orow = (size_t)(rb + ty * 8 + i) * N + nb + tx * 8;
#pragma unroll
    for (int j = 0; j < 8; ++j) {
      float x = acc[i][j] + bias[nb + tx * 8 + j];
      x = (x > 0.f) ? x : expm1f(x);
      Out[orow + j] = x;
    }
  }
}

// ------- gate head: logits, softmax, top-2, perm lists, aux accum -------
// Hierarchical slot reservation: LDS-local offsets, one global atomic per
// expert per block (fixes round-3's 290us same-address atomic serialization).
#define ACTION_SZ (32768 * 12)
#define AUX_OFF   ACTION_SZ
#define IDX_OFF   (ACTION_SZ + 1)
#define SCO_OFF   (ACTION_SZ + 1 + 32768 * 2)

__global__ void k_gatetop(const float* __restrict__ gh2,
                          const float* __restrict__ gw3, const float* __restrict__ gb3,
                          float* __restrict__ out, float* __restrict__ aux,
                          int* __restrict__ cnt, int* __restrict__ perm,
                          float* __restrict__ selbuf) {
  int tid = threadIdx.x;
  int b = blockIdx.x * 256 + tid;
  __shared__ int scnt[8], sbase[8];
  __shared__ float sprob[8];
  if (tid < 8) { scnt[tid] = 0; sprob[tid] = 0.f; }
  __syncthreads();

  float lg[8];
#pragma unroll
  for (int j = 0; j < 8; ++j) lg[j] = gb3[j];
  for (int k = 0; k < 128; ++k) {
    float h = gh2[(size_t)b * 128 + k];
#pragma unroll
    for (int j = 0; j < 8; ++j) lg[j] += h * gw3[k * 8 + j];
  }
  float m = lg[0];
#pragma unroll
  for (int j = 1; j < 8; ++j) m = fmaxf(m, lg[j]);
  float probs[8], sum = 0.f;
#pragma unroll
  for (int j = 0; j < 8; ++j) { float p = expf(lg[j] - m); probs[j] = p; sum += p; }
  float inv = 1.f / sum;
#pragma unroll
  for (int j = 0; j < 8; ++j) probs[j] *= inv;
  int i0 = 0, i1;
  float v0 = -1e30f;
#pragma unroll
  for (int j = 0; j < 8; ++j) if (probs[j] > v0) { v0 = probs[j]; i0 = j; }
  float v1 = -1e30f; i1 = (i0 == 0) ? 1 : 0;
#pragma unroll
  for (int j = 0; j < 8; ++j) if (j != i0 && probs[j] > v1) { v1 = probs[j]; i1 = j; }
  float wsum = v0 + v1 + 1e-9f;
  float w0 = v0 / wsum, w1 = v1 / wsum;

  out[IDX_OFF + (size_t)b * 2 + 0] = (float)i0;
  out[IDX_OFF + (size_t)b * 2 + 1] = (float)i1;
  out[SCO_OFF + (size_t)b * 2 + 0] = v0;
  out[SCO_OFF + (size_t)b * 2 + 1] = v1;
  selbuf[(size_t)b * 4 + 0] = (float)i0;
  selbuf[(size_t)b * 4 + 1] = (float)i1;
  selbuf[(size_t)b * 4 + 2] = w0;
  selbuf[(size_t)b * 4 + 3] = w1;

  // local slot numbers within the block (LDS atomics, low contention)
  int l0 = atomicAdd(&scnt[i0], 1);
  int l1 = atomicAdd(&scnt[i1], 1);

  // aux prob sums: wave-reduce then LDS accumulate
  int lane = tid & 63;
#pragma unroll
  for (int j = 0; j < 8; ++j) {
    float p = probs[j];
#pragma unroll
    for (int mk = 1; mk <= 32; mk <<= 1) p += __shfl_xor(p, mk, 64);
    if (lane == 0) atomicAdd(&sprob[j], p);
  }
  __syncthreads();

  // one global reservation per expert per block
  if (tid < 8) {
    sbase[tid] = atomicAdd(&cnt[tid], scnt[tid]);
    atomicAdd(&aux[tid], sprob[tid]);
  }
  __syncthreads();

  int s0 = sbase[i0] + l0;
  if (s0 < CAP) perm[i0 * CAP + s0] = b;
  int s1 = sbase[i1] + l1;
  if (s1 < CAP) perm[i1 * CAP + s1] = b;
}

__global__ void k_auxfinal(const int* __restrict__ cnt, const float* __restrict__ aux,
                           float* __restrict__ out) {
  if (threadIdx.x == 0) {
    float s = 0.f;
#pragma unroll
    for (int e = 0; e < 8; ++e) {
      float f = (float)cnt[e] / (32768.f * 2.f);
      float P = aux[e] / 32768.f;
      s += f * P;
    }
    out[AUX_OFF] = 8.f * s;
  }
}

// ------- expert layer: Out = LN(ELU(A@W + b)), gathered rows -------
template<int KD, int ND, bool GATHER>
__launch_bounds__(512, 4)
__global__ void k_layer(const unsigned short* __restrict__ A, int As,
                        const int* __restrict__ perm, const int* __restrict__ cnt,
                        const unsigned short* __restrict__ Wt,
                        const float* __restrict__ bias,
                        const float* __restrict__ gamma,
                        const float* __restrict__ beta,
                        unsigned short* __restrict__ Out, int Os, int Ocol) {
  constexpr int WC = ND / 4;
  constexpr int NF = WC / 16;
  constexpr int NK = KD / 64;
  static_assert(NF >= 1 && KD % 64 == 0, "shape");

  int e = blockIdx.y;
  int count = cnt[e]; if (count > CAP) count = CAP;
  int rb = blockIdx.x * 64;
  if (rb >= count) return;

  __shared__ unsigned short smem[2][64 * 64];
  __shared__ float red[64][4][2];

  int tid = threadIdx.x;
  int lane = tid & 63, wid = tid >> 6;
  int wm = wid >> 2, wn = wid & 3;

  const unsigned short* We = Wt + (size_t)e * ND * KD;
  const float* biasv = bias + e * ND;
  const float* gamv = gamma + e * ND;
  const float* betv = beta + e * ND;

  int srow = tid >> 3, schunk = tid & 7;
  int slot = rb + srow;
  size_t arow;
  if (GATHER) {
    int s = slot < count ? slot : count - 1;
    arow = (size_t)perm[e * CAP + s];
  } else {
    arow = (size_t)e * CAP + slot;
  }
  const unsigned short* aptr = A + arow * As + schunk * 8;
  int lws = srow * 64 + ((schunk ^ (srow & 7)) << 3);

  f32x4 acc[2][NF] = {};

  {
    uint4 v = *(const uint4*)(aptr);
    *(uint4*)(&smem[0][lws]) = v;
  }
  __syncthreads();

  int l15 = lane & 15, g = lane >> 4;
  for (int kt = 0; kt < NK; ++kt) {
    int buf = kt & 1;
    if (kt + 1 < NK) {
      uint4 v = *(const uint4*)(aptr + (kt + 1) * 64);
      *(uint4*)(&smem[buf ^ 1][lws]) = v;
    }
#pragma unroll
    for (int kk = 0; kk < 2; ++kk) {
      bf16x8 a[2];
#pragma unroll
      for (int mf = 0; mf < 2; ++mf) {
        int row = wm * 32 + mf * 16 + l15;
        int chunk = (kk * 4 + g) ^ (row & 7);
        a[mf] = *(const bf16x8*)(&smem[buf][row * 64 + chunk * 8]);
      }
#pragma unroll
      for (int nf = 0; nf < NF; ++nf) {
        int n = wn * WC + nf * 16 + l15;
        bf16x8 b = *(const bf16x8*)(We + (size_t)n * KD + kt * 64 + kk * 32 + g * 8);
        acc[0][nf] = __builtin_amdgcn_mfma_f32_16x16x32_bf16(a[0], b, acc[0][nf], 0, 0, 0);
        acc[1][nf] = __builtin_amdgcn_mfma_f32_16x16x32_bf16(a[1], b, acc[1][nf], 0, 0, 0);
      }
    }
    __syncthreads();
  }

  float bia[NF], gam[NF], bet[NF];
#pragma unroll
  for (int nf = 0; nf < NF; ++nf) {
    int n = wn * WC + nf * 16 + l15;
    bia[nf] = biasv[n]; gam[nf] = gamv[n]; bet[nf] = betv[n];
  }
#pragma unroll
  for (int mf = 0; mf < 2; ++mf)
#pragma unroll
    for (int nf = 0; nf < NF; ++nf)
#pragma unroll
      for (int r = 0; r < 4; ++r) {
        float x = acc[mf][nf][r] + bia[nf];
        x = (x > 0.f) ? x : expm1f(x);
        acc[mf][nf][r] = x;
      }
#pragma unroll
  for (int mf = 0; mf < 2; ++mf)
#pragma unroll
    for (int r = 0; r < 4; ++r) {
      float s1 = 0.f, s2 = 0.f;
#pragma unroll
      for (int nf = 0; nf < NF; ++nf) {
        float x = acc[mf][nf][r];
        s1 += x; s2 += x * x;
      }
#pragma unroll
      for (int m = 1; m <= 8; m <<= 1) {
        s1 += __shfl_xor(s1, m, 64);
        s2 += __shfl_xor(s2, m, 64);
      }
      if (l15 == 0) {
        int row = wm * 32 + mf * 16 + g * 4 + r;
        red[row][wn][0] = s1;
        red[row][wn][1] = s2;
      }
    }
  __syncthreads();
  const float invn = 1.f / (float)ND;
#pragma unroll
  for (int mf = 0; mf < 2; ++mf)
#pragma unroll
    for (int r = 0; r < 4; ++r) {
      int row = wm * 32 + mf * 16 + g * 4 + r;
      float s1 = red[row][0][0] + red[row][1][0] + red[row][2][0] + red[row][3][0];
      float s2 = red[row][0][1] + red[row][1][1] + red[row][2][1] + red[row][3][1];
      float mean = s1 * invn;
      float var = s2 * invn - mean * mean;
      float rstd = rsqrtf(var + 1e-5f);
      size_t orow = ((size_t)e * CAP + rb + row) * Os + Ocol;
#pragma unroll
      for (int nf = 0; nf < NF; ++nf) {
        float y = (acc[mf][nf][r] - mean) * rstd * gam[nf] + bet[nf];
        Out[orow + wn * WC + nf * 16 + l15] = f2b(y);
      }
    }
}

// ------- final expert layer 256 -> 12, scatter to allout -------
__global__ void k_out12(const unsigned short* __restrict__ f2buf,
                        const int* __restrict__ perm, const int* __restrict__ cnt,
                        const float* __restrict__ fw3, const float* __restrict__ fb3,
                        float* __restrict__ allout) {
  int e = blockIdx.y;
  int count = cnt[e]; if (count > CAP) count = CAP;
  int rb = blockIdx.x * 16;
  if (rb >= count) return;
  __shared__ unsigned short rowbuf[16 * 256];
  __shared__ float wsh[256 * 12];
  int tid = threadIdx.x; // 256
  {
    int row = tid >> 4, c0 = (tid & 15) * 16;
    const unsigned short* src = f2buf + ((size_t)e * CAP + rb + row) * 256 + c0;
    *(uint4*)(&rowbuf[row * 256 + c0]) = *(const uint4*)(src);
    *(uint4*)(&rowbuf[row * 256 + c0 + 8]) = *(const uint4*)(src + 8);
  }
  for (int i = tid; i < 256 * 12; i += 256) wsh[i] = fw3[(size_t)e * 256 * 12 + i];
  __syncthreads();
  int r = tid >> 4, j = tid & 15;
  int slot = rb + r;
  if (j < 12 && slot < count) {
    float acc = fb3[e * 12 + j];
    for (int k = 0; k < 256; ++k)
      acc += b2f(rowbuf[r * 256 + k]) * wsh[k * 12 + j];
    int arow = perm[e * CAP + slot];
    allout[((size_t)arow * 8 + e) * 12 + j] = acc;
  }
}

// ------- mix: weighted sum of the two selected expert outputs -------
__global__ void k_mix(const float* __restrict__ selbuf, const float* __restrict__ allout,
                      float* __restrict__ out) {
  int b = blockIdx.x * 256 + threadIdx.x;
  int i0 = (int)selbuf[(size_t)b * 4 + 0];
  int i1 = (int)selbuf[(size_t)b * 4 + 1];
  float w0 = selbuf[(size_t)b * 4 + 2];
  float w1 = selbuf[(size_t)b * 4 + 3];
  const float* a0 = allout + ((size_t)b * 8 + i0) * 12;
  const float* a1 = allout + ((size_t)b * 8 + i1) * 12;
#pragma unroll
  for (int j = 0; j < 12; ++j)
    out[(size_t)b * 12 + j] = w0 * a0[j] + w1 * a1[j];
}

// ---------------- host ----------------

extern "C" void kernel_launch(void* const* d_in, const int* in_sizes, int n_in,
                              void* d_out, int out_size, void* d_ws, size_t ws_size,
                              hipStream_t stream) {
  const float* state = (const float*)d_in[0];
  const float* vlm   = (const float*)d_in[1];
  const float* sw1 = (const float*)d_in[2];  const float* sb1 = (const float*)d_in[3];
  const float* sg1 = (const float*)d_in[4];  const float* sh1 = (const float*)d_in[5];
  const float* sw2 = (const float*)d_in[6];  const float* sb2 = (const float*)d_in[7];
  const float* sg2 = (const float*)d_in[8];  const float* sh2 = (const float*)d_in[9];
  const float* vw1 = (const float*)d_in[10]; const float* vb1 = (const float*)d_in[11];
  const float* vg1 = (const float*)d_in[12]; const float* vh1 = (const float*)d_in[13];
  const float* vw2 = (const float*)d_in[14]; const float* vb2 = (const float*)d_in[15];
  const float* vg2 = (const float*)d_in[16]; const float* vh2 = (const float*)d_in[17];
  const float* fw1 = (const float*)d_in[18]; const float* fb1 = (const float*)d_in[19];
  const float* fg1 = (const float*)d_in[20]; const float* fh1 = (const float*)d_in[21];
  const float* fw2 = (const float*)d_in[22]; const float* fb2 = (const float*)d_in[23];
  const float* fg2 = (const float*)d_in[24]; const float* fh2 = (const float*)d_in[25];
  const float* fw3 = (const float*)d_in[26]; const float* fb3 = (const float*)d_in[27];
  const float* gw1 = (const float*)d_in[28]; const float* gb1 = (const float*)d_in[29];
  const float* gw2 = (const float*)d_in[30]; const float* gb2 = (const float*)d_in[31];
  const float* gw3 = (const float*)d_in[32]; const float* gb3 = (const float*)d_in[33];

  // ---- workspace layout with lifetime-based aliasing (~236 MB total) ----
  char* ws = (char*)d_ws;
  size_t off = 0;
  auto alloc = [&](size_t bytes) -> char* {
    char* p = ws + off;
    off = (off + bytes + 255) & ~(size_t)255;
    return p;
  };
  const size_t SZ_bufA = (size_t)NEXP * CAP * 512 * 2;  // 83.9 MB
  const size_t SZ_gh1  = (size_t)BROWS * 256 * 4;       // 33.6 MB
  const size_t SZ_gh2  = (size_t)BROWS * 128 * 4;       // 16.8 MB

  char* regA = alloc(SZ_bufA);
  unsigned short* bufA  = (unsigned short*)regA;              // h1v / f1b (expert phase)
  float* gh1            = (float*)regA;                       // gate phase only
  float* gh2            = (float*)(regA + SZ_gh1);            // gate phase only
  unsigned short* st_bf = (unsigned short*)(regA + SZ_gh1 + SZ_gh2); // dead after s1 (< v1)

  unsigned short* bufF = (unsigned short*)alloc((size_t)NEXP * CAP * 384 * 2); // 62.9 MB
  unsigned short* bufC = (unsigned short*)alloc((size_t)NEXP * CAP * 256 * 2); // 41.9 MB

  char* regV = alloc((size_t)BROWS * 512 * 2);                 // 33.6 MB
  unsigned short* vl_bf = (unsigned short*)regV;               // dead after v1
  float* allout         = (float*)regV;                        // written at out12 (after v1)

  float* selbuf = (float*)alloc((size_t)BROWS * 4 * 4);
  int*   perm   = (int*)alloc((size_t)NEXP * CAP * 4);
  char*  cntaux = alloc(256);  // cnt: 8 ints at +0, aux: 8 floats at +64
  int*   cnt = (int*)cntaux;
  float* aux = (float*)(cntaux + 64);
  unsigned short* wt_s1 = (unsigned short*)alloc((size_t)8 * 256 * 128 * 2);
  unsigned short* wt_s2 = (unsigned short*)alloc((size_t)8 * 128 * 256 * 2);
  unsigned short* wt_v1 = (unsigned short*)alloc((size_t)8 * 512 * 512 * 2);
  unsigned short* wt_v2 = (unsigned short*)alloc((size_t)8 * 256 * 512 * 2);
  unsigned short* wt_f1 = (unsigned short*)alloc((size_t)8 * 512 * 384 * 2);
  unsigned short* wt_f2 = (unsigned short*)alloc((size_t)8 * 256 * 512 * 2);
  (void)ws_size; (void)in_sizes; (void)n_in; (void)out_size;

  float* outf = (float*)d_out;

  // prep
  k_convert_pad<<<(BROWS * 128 + 255) / 256, 256, 0, stream>>>(state, st_bf, BROWS, 96, 128);
  k_convert_pad<<<(BROWS * 512 + 255) / 256, 256, 0, stream>>>(vlm, vl_bf, BROWS, 512, 512);
  k_wtrans<<<dim3(4, 8, 8),   dim3(32, 8), 0, stream>>>(sw1, wt_s1, 96, 256, 128);
  k_wtrans<<<dim3(8, 4, 8),   dim3(32, 8), 0, stream>>>(sw2, wt_s2, 256, 128, 256);
  k_wtrans<<<dim3(16, 16, 8), dim3(32, 8), 0, stream>>>(vw1, wt_v1, 512, 512, 512);
  k_wtrans<<<dim3(16, 8, 8),  dim3(32, 8), 0, stream>>>(vw2, wt_v2, 512, 256, 512);
  k_wtrans<<<dim3(12, 16, 8), dim3(32, 8), 0, stream>>>(fw1, wt_f1, 384, 512, 384);
  k_wtrans<<<dim3(16, 8, 8),  dim3(32, 8), 0, stream>>>(fw2, wt_f2, 512, 256, 512);
  k_zero<<<1, 64, 0, stream>>>((int*)cntaux, 64);

  // gate (fp32 for exact top-k); gh1/gh2 live inside bufA region (pre-expert phase)
  k_gemm32<true><<<dim3(256, 2), 256, 0, stream>>>(state, 96, vlm, 512, 96,
                                                   gw1, gb1, 608, 256, gh1);
  k_gemm32<false><<<dim3(256, 1), 256, 0, stream>>>(gh1, 256, nullptr, 0, 0,
                                                    gw2, gb2, 256, 128, gh2);
  k_gatetop<<<BROWS / 256, 256, 0, stream>>>(gh2, gw3, gb3, outf, aux, cnt, perm, selbuf);
  k_auxfinal<<<1, 64, 0, stream>>>(cnt, aux, outf);

  // experts: s-layers first (st_bf aliases bufA tail; must finish before v1 writes bufA)
  dim3 lg(CAPBLK, NEXP);
  k_layer<128, 256, true><<<lg, 512, 0, stream>>>(st_bf, 128, perm, cnt, wt_s1,
      sb1, sg1, sh1, bufC, 256, 0);
  k_layer<256, 128, false><<<lg, 512, 0, stream>>>(bufC, 256, perm, cnt, wt_s2,
      sb2, sg2, sh2, bufF, 384, 0);
  k_layer<512, 512, true><<<lg, 512, 0, stream>>>(vl_bf, 512, perm, cnt, wt_v1,
      vb1, vg1, vh1, bufA, 512, 0);
  k_layer<512, 256, false><<<lg, 512, 0, stream>>>(bufA, 512, perm, cnt, wt_v2,
      vb2, vg2, vh2, bufF, 384, 128);
  k_layer<384, 512, false><<<lg, 512, 0, stream>>>(bufF, 384, perm, cnt, wt_f1,
      fb1, fg1, fh1, bufA, 512, 0);
  k_layer<512, 256, false><<<lg, 512, 0, stream>>>(bufA, 512, perm, cnt, wt_f2,
      fb2, fg2, fh2, bufC, 256, 0);
  k_out12<<<dim3(CAP / 16, NEXP), 256, 0, stream>>>(bufC, perm, cnt, fw3, fb3, allout);

  k_mix<<<BROWS / 256, 256, 0, stream>>>(selbuf, allout, outf);
}

// Round 5
// 867.321 us; speedup vs baseline: 3.2484x; 1.1771x over previous
//
#include <hip/hip_runtime.h>
#include <cstdint>
#include <cstddef>

#define BROWS 32768
#define NEXP 8
#define CAP 10240          // per-expert row capacity (E[count]=8192, std~78)
#define CAPBLK (CAP / 64)

typedef short bf16x8 __attribute__((ext_vector_type(8)));
typedef float f32x4 __attribute__((ext_vector_type(4)));

__device__ __forceinline__ unsigned short f2b(float f) {
  union { float f; unsigned u; } v; v.f = f;
  unsigned r = (v.u + 0x7fffu + ((v.u >> 16) & 1u)) >> 16;
  return (unsigned short)r;
}
__device__ __forceinline__ float b2f(unsigned short s) {
  union { unsigned u; float f; } v; v.u = ((unsigned)s) << 16; return v.f;
}

// ---------------- prep kernels ----------------

__global__ void k_convert_pad(const float* __restrict__ src, unsigned short* __restrict__ dst,
                              int rows, int sc, int dc) {
  int i = blockIdx.x * 256 + threadIdx.x;
  if (i >= rows * dc) return;
  int r = i / dc, c = i % dc;
  float v = (c < sc) ? src[(size_t)r * sc + c] : 0.f;
  dst[i] = f2b(v);
}

// src f32 [E][K][N] -> dst bf16 [E][N][Kpad]
__global__ void k_wtrans(const float* __restrict__ src, unsigned short* __restrict__ dst,
                         int K, int N, int Kpad) {
  __shared__ float tile[32][33];
  int e = blockIdx.z;
  int k0 = blockIdx.x * 32, n0 = blockIdx.y * 32;
  int tx = threadIdx.x, ty = threadIdx.y; // 32 x 8
  for (int i = 0; i < 32; i += 8) {
    int k = k0 + ty + i;
    tile[ty + i][tx] = (k < K) ? src[((size_t)e * K + k) * N + n0 + tx] : 0.f;
  }
  __syncthreads();
  for (int i = 0; i < 32; i += 8) {
    int n = n0 + ty + i;
    dst[((size_t)e * N + n) * Kpad + k0 + tx] = f2b(tile[tx][ty + i]);
  }
}

__global__ void k_zero(int* p, int n) {
  int i = blockIdx.x * 64 + threadIdx.x;
  if (i < n) p[i] = 0;
}

// ---------------- fp32 gate GEMM: Out = ELU(A@W + bias) ----------------
template<bool TWOSRC>
__launch_bounds__(256, 2)
__global__ void k_gemm32(const float* __restrict__ A0, int As0,
                         const float* __restrict__ A1, int As1, int Ks,
                         const float* __restrict__ W, const float* __restrict__ bias,
                         int K, int N, float* __restrict__ Out) {
  __shared__ float Asub[128][33];
  __shared__ float Bsub[32][132];
  int tid = threadIdx.x;
  int rb = blockIdx.x * 128, nb = blockIdx.y * 128;
  int tx = tid & 15, ty = tid >> 4;
  float acc[8][8] = {};

  int ar = tid >> 1, akoff = (tid & 1) * 16;
  int bkr = tid >> 3, bc0 = (tid & 7) * 16;

  for (int k0 = 0; k0 < K; k0 += 32) {
#pragma unroll
    for (int i = 0; i < 4; ++i) {
      int k = k0 + akoff + i * 4;
      float4 v;
      if (!TWOSRC || k < Ks)
        v = *(const float4*)(A0 + (size_t)(rb + ar) * As0 + k);
      else
        v = *(const float4*)(A1 + (size_t)(rb + ar) * As1 + (k - Ks));
      Asub[ar][akoff + i * 4 + 0] = v.x;
      Asub[ar][akoff + i * 4 + 1] = v.y;
      Asub[ar][akoff + i * 4 + 2] = v.z;
      Asub[ar][akoff + i * 4 + 3] = v.w;
    }
#pragma unroll
    for (int i = 0; i < 4; ++i) {
      float4 v = *(const float4*)(W + (size_t)(k0 + bkr) * N + nb + bc0 + i * 4);
      *(float4*)(&Bsub[bkr][bc0 + i * 4]) = v;
    }
    __syncthreads();
#pragma unroll 4
    for (int kk = 0; kk < 32; ++kk) {
      float4 b0 = *(const float4*)(&Bsub[kk][tx * 8]);
      float4 b1 = *(const float4*)(&Bsub[kk][tx * 8 + 4]);
      float bv[8] = {b0.x, b0.y, b0.z, b0.w, b1.x, b1.y, b1.z, b1.w};
      float av[8];
#pragma unroll
      for (int i = 0; i < 8; ++i) av[i] = Asub[ty * 8 + i][kk];
#pragma unroll
      for (int i = 0; i < 8; ++i)
#pragma unroll
        for (int j = 0; j < 8; ++j) acc[i][j] += av[i] * bv[j];
    }
    __syncthreads();
  }
#pragma unroll
  for (int i = 0; i < 8; ++i) {
    size_t orow = (size_t)(rb + ty * 8 + i) * N + nb + tx * 8;
#pragma unroll
    for (int j = 0; j < 8; ++j) {
      float x = acc[i][j] + bias[nb + tx * 8 + j];
      x = (x > 0.f) ? x : expm1f(x);
      Out[orow + j] = x;
    }
  }
}

// ------- gate head: logits, softmax, top-2; per-wave-group counts -------
#define ACTION_SZ (32768 * 12)
#define AUX_OFF   ACTION_SZ
#define IDX_OFF   (ACTION_SZ + 1)
#define SCO_OFF   (ACTION_SZ + 1 + 32768 * 2)

__global__ void k_gatetop(const float* __restrict__ gh2,
                          const float* __restrict__ gw3, const float* __restrict__ gb3,
                          float* __restrict__ out, float* __restrict__ aux,
                          int* __restrict__ bcnt, float* __restrict__ selbuf) {
  int tid = threadIdx.x;
  int b = blockIdx.x * 256 + tid;
  int lane = tid & 63, w = tid >> 6;
  __shared__ float sprob[8];
  if (tid < 8) sprob[tid] = 0.f;
  __syncthreads();

  float lg[8];
#pragma unroll
  for (int j = 0; j < 8; ++j) lg[j] = gb3[j];
  for (int k = 0; k < 128; ++k) {
    float h = gh2[(size_t)b * 128 + k];
#pragma unroll
    for (int j = 0; j < 8; ++j) lg[j] += h * gw3[k * 8 + j];
  }
  float m = lg[0];
#pragma unroll
  for (int j = 1; j < 8; ++j) m = fmaxf(m, lg[j]);
  float probs[8], sum = 0.f;
#pragma unroll
  for (int j = 0; j < 8; ++j) { float p = expf(lg[j] - m); probs[j] = p; sum += p; }
  float inv = 1.f / sum;
#pragma unroll
  for (int j = 0; j < 8; ++j) probs[j] *= inv;
  int i0 = 0, i1;
  float v0 = -1e30f;
#pragma unroll
  for (int j = 0; j < 8; ++j) if (probs[j] > v0) { v0 = probs[j]; i0 = j; }
  float v1 = -1e30f; i1 = (i0 == 0) ? 1 : 0;
#pragma unroll
  for (int j = 0; j < 8; ++j) if (j != i0 && probs[j] > v1) { v1 = probs[j]; i1 = j; }
  float wsum = v0 + v1 + 1e-9f;
  float w0 = v0 / wsum, w1 = v1 / wsum;

  out[IDX_OFF + (size_t)b * 2 + 0] = (float)i0;
  out[IDX_OFF + (size_t)b * 2 + 1] = (float)i1;
  out[SCO_OFF + (size_t)b * 2 + 0] = v0;
  out[SCO_OFF + (size_t)b * 2 + 1] = v1;
  selbuf[(size_t)b * 4 + 0] = (float)i0;
  selbuf[(size_t)b * 4 + 1] = (float)i1;
  selbuf[(size_t)b * 4 + 2] = w0;
  selbuf[(size_t)b * 4 + 3] = w1;

  // per-64-row-group expert counts via ballot (deterministic, no atomics)
#pragma unroll
  for (int e2 = 0; e2 < 8; ++e2) {
    unsigned long long mm = __ballot(i0 == e2) | __ballot(i1 == e2);
    if (lane == 0) bcnt[(blockIdx.x * 4 + w) * 8 + e2] = __popcll(mm);
  }

  // aux prob sums: wave-reduce -> LDS -> one atomic per block per expert
#pragma unroll
  for (int j = 0; j < 8; ++j) {
    float p = probs[j];
#pragma unroll
    for (int mk = 1; mk <= 32; mk <<= 1) p += __shfl_xor(p, mk, 64);
    if (lane == 0) atomicAdd(&sprob[j], p);
  }
  __syncthreads();
  if (tid < 8) atomicAdd(&aux[tid], sprob[tid]);
}

// exclusive scan of bcnt over 512 groups per expert -> bbase, totals -> cnt
__global__ void k_scan(const int* __restrict__ bcnt, int* __restrict__ bbase,
                       int* __restrict__ cnt) {
  int e2 = threadIdx.x;
  if (e2 < 8) {
    int run = 0;
    for (int gidx = 0; gidx < 512; ++gidx) {
      bbase[gidx * 8 + e2] = run;
      run += bcnt[gidx * 8 + e2];
    }
    cnt[e2] = run;
  }
}

// fill perm sorted by row within each expert (deterministic, ballot ranks)
__global__ void k_fill(const float* __restrict__ selbuf, const int* __restrict__ bbase,
                       int* __restrict__ perm) {
  int gidx = blockIdx.x;          // 512 groups
  int lane = threadIdx.x;         // 64
  int b = gidx * 64 + lane;
  int i0 = (int)selbuf[(size_t)b * 4 + 0];
  int i1 = (int)selbuf[(size_t)b * 4 + 1];
  unsigned long long lt = (1ull << lane) - 1ull;
#pragma unroll
  for (int e2 = 0; e2 < 8; ++e2) {
    unsigned long long mm = __ballot(i0 == e2) | __ballot(i1 == e2);
    if (i0 == e2 || i1 == e2) {
      int s = bbase[gidx * 8 + e2] + (int)__popcll(mm & lt);
      if (s < CAP) perm[e2 * CAP + s] = b;
    }
  }
}

__global__ void k_auxfinal(const int* __restrict__ cnt, const float* __restrict__ aux,
                           float* __restrict__ out) {
  if (threadIdx.x == 0) {
    float s = 0.f;
#pragma unroll
    for (int e = 0; e < 8; ++e) {
      float f = (float)cnt[e] / (32768.f * 2.f);
      float P = aux[e] / 32768.f;
      s += f * P;
    }
    out[AUX_OFF] = 8.f * s;
  }
}

// ------- expert layer: Out = LN(ELU(A@W + b)), gathered rows -------
// 8 waves, 1M x 8N decomposition: each wave owns WC = ND/8 cols, all 64 rows.
// B frags register-prefetched; A tile dbuf LDS with T14 issue-early/write-late.
// Epilogue: LDS-staged vectorized (dwordx4) stores.
template<int KD, int ND, bool GATHER>
__launch_bounds__(512, (ND >= 512) ? 3 : 4)
__global__ void k_layer(const unsigned short* __restrict__ A, int As,
                        const int* __restrict__ perm, const int* __restrict__ cnt,
                        const unsigned short* __restrict__ Wt,
                        const float* __restrict__ bias,
                        const float* __restrict__ gamma,
                        const float* __restrict__ beta,
                        unsigned short* __restrict__ Out, int Os, int Ocol) {
  constexpr int WC = ND / 8;     // cols per wave
  constexpr int NF = WC / 16;    // 16-col frags per wave (4/2/1)
  constexpr int NK = KD / 64;    // K tiles
  constexpr int NCH = ND / 128;  // 128-col store chunks (>=1)
  static_assert(NF >= 1 && KD % 64 == 0 && ND % 128 == 0, "shape");

  __shared__ unsigned short smem[2][64 * 64];
  __shared__ float red[64][8][2];
  __shared__ float rowstat[64][2];

  int e = blockIdx.y;
  int count = cnt[e]; if (count > CAP) count = CAP;
  int rb = blockIdx.x * 64;
  if (rb >= count) return;

  int tid = threadIdx.x;
  int lane = tid & 63, wn = tid >> 6;
  int l15 = lane & 15, g = lane >> 4;

  const unsigned short* We = Wt + (size_t)e * ND * KD;

  // A staging: 512 thr x 16B = 64 rows x 64 bf16
  int srow = tid >> 3, schunk = tid & 7;
  int slot = rb + srow;
  size_t arow;
  if (GATHER) {
    int s = slot < count ? slot : count - 1;
    arow = (size_t)perm[e * CAP + s];
  } else {
    arow = (size_t)e * CAP + slot;
  }
  const unsigned short* aptr = A + arow * As + schunk * 8;
  int lws = srow * 64 + ((schunk ^ (srow & 7)) << 3);

  // B frag base pointers (per nf)
  const unsigned short* bp[NF];
#pragma unroll
  for (int nf = 0; nf < NF; ++nf)
    bp[nf] = We + (size_t)(wn * WC + nf * 16 + l15) * KD + g * 8;

  f32x4 acc[4][NF] = {};

  // prologue: stage A tile 0; preload B(kt=0,kk=0)
  { uint4 v = *(const uint4*)(aptr); *(uint4*)(&smem[0][lws]) = v; }
  bf16x8 bq[NF];
#pragma unroll
  for (int nf = 0; nf < NF; ++nf) bq[nf] = *(const bf16x8*)(bp[nf]);
  __syncthreads();

  for (int kt = 0; kt < NK; ++kt) {
    int buf = kt & 1;
    uint4 vnext;
    if (kt + 1 < NK) vnext = *(const uint4*)(aptr + (kt + 1) * 64);  // issue early
#pragma unroll
    for (int kk = 0; kk < 2; ++kk) {
      bf16x8 a4[4];
#pragma unroll
      for (int mf = 0; mf < 4; ++mf) {
        int row = mf * 16 + l15;
        int chunk = (kk * 4 + g) ^ (row & 7);
        a4[mf] = *(const bf16x8*)(&smem[buf][row * 64 + chunk * 8]);
      }
      bool has_next = (kk == 0) || (kt + 1 < NK);
      int noff = (kk == 0) ? (kt * 64 + 32) : ((kt + 1) * 64);
      bf16x8 bn[NF];
      if (has_next) {
#pragma unroll
        for (int nf = 0; nf < NF; ++nf) bn[nf] = *(const bf16x8*)(bp[nf] + noff);
      }
#pragma unroll
      for (int nf = 0; nf < NF; ++nf)
#pragma unroll
        for (int mf = 0; mf < 4; ++mf)
          acc[mf][nf] = __builtin_amdgcn_mfma_f32_16x16x32_bf16(a4[mf], bq[nf], acc[mf][nf], 0, 0, 0);
      if (has_next) {
#pragma unroll
        for (int nf = 0; nf < NF; ++nf) bq[nf] = bn[nf];
      }
    }
    if (kt + 1 < NK) *(uint4*)(&smem[buf ^ 1][lws]) = vnext;  // write late
    __syncthreads();
  }

  // ---- epilogue: bias + ELU ----
  float bia[NF], gam[NF], bet[NF];
#pragma unroll
  for (int nf = 0; nf < NF; ++nf) {
    int n = wn * WC + nf * 16 + l15;
    bia[nf] = bias[e * ND + n]; gam[nf] = gamma[e * ND + n]; bet[nf] = beta[e * ND + n];
  }
#pragma unroll
  for (int mf = 0; mf < 4; ++mf)
#pragma unroll
    for (int nf = 0; nf < NF; ++nf)
#pragma unroll
      for (int r = 0; r < 4; ++r) {
        float x = acc[mf][nf][r] + bia[nf];
        x = (x > 0.f) ? x : expm1f(x);
        acc[mf][nf][r] = x;
      }

  // ---- fused LN: per-row partials -> rowstat ----
#pragma unroll
  for (int mf = 0; mf < 4; ++mf)
#pragma unroll
    for (int r = 0; r < 4; ++r) {
      float s1 = 0.f, s2 = 0.f;
#pragma unroll
      for (int nf = 0; nf < NF; ++nf) {
        float x = acc[mf][nf][r];
        s1 += x; s2 += x * x;
      }
#pragma unroll
      for (int mk = 1; mk <= 8; mk <<= 1) {
        s1 += __shfl_xor(s1, mk, 64);
        s2 += __shfl_xor(s2, mk, 64);
      }
      if (l15 == 0) {
        int row = mf * 16 + g * 4 + r;
        red[row][wn][0] = s1;
        red[row][wn][1] = s2;
      }
    }
  __syncthreads();
  if (tid < 64) {
    float s1 = 0.f, s2 = 0.f;
#pragma unroll
    for (int j = 0; j < 8; ++j) { s1 += red[tid][j][0]; s2 += red[tid][j][1]; }
    float mean = s1 / (float)ND;
    float var = s2 / (float)ND - mean * mean;
    rowstat[tid][0] = mean;
    rowstat[tid][1] = rsqrtf(var + 1e-5f);
  }
  __syncthreads();
#pragma unroll
  for (int mf = 0; mf < 4; ++mf)
#pragma unroll
    for (int r = 0; r < 4; ++r) {
      int row = mf * 16 + g * 4 + r;
      float mean = rowstat[row][0], rstd = rowstat[row][1];
#pragma unroll
      for (int nf = 0; nf < NF; ++nf)
        acc[mf][nf][r] = (acc[mf][nf][r] - mean) * rstd * gam[nf] + bet[nf];
    }

  // ---- vectorized store via LDS staging, 128-col chunks ----
  unsigned short* sm16 = &smem[0][0];   // [64][128]
  int wq = (wn * WC) >> 7;              // this wave's chunk index
  for (int q = 0; q < NCH; ++q) {
    if (NCH == 1 || wq == q) {
#pragma unroll
      for (int mf = 0; mf < 4; ++mf)
#pragma unroll
        for (int r = 0; r < 4; ++r) {
          int row = mf * 16 + g * 4 + r;
          int s = row & 7;
#pragma unroll
          for (int nf = 0; nf < NF; ++nf) {
            int lc = (wn * WC + nf * 16 + l15) - q * 128;   // 0..127
            int pos = (((lc >> 3) ^ s) << 3) | (lc & 7);
            sm16[row * 128 + pos] = f2b(acc[mf][nf][r]);
          }
        }
    }
    __syncthreads();
#pragma unroll
    for (int i = 0; i < 2; ++i) {
      int t = tid + i * 512;            // 1024 chunks of 8 elems
      int row = t >> 4, cc = t & 15;
      int oc = cc ^ (row & 7);
      uint4 v = *(const uint4*)(&sm16[row * 128 + cc * 8]);
      *(uint4*)(&Out[((size_t)e * CAP + rb + row) * Os + Ocol + q * 128 + oc * 8]) = v;
    }
    __syncthreads();
  }
}

// ------- final expert layer 256 -> 12, scatter to allout -------
__global__ void k_out12(const unsigned short* __restrict__ f2buf,
                        const int* __restrict__ perm, const int* __restrict__ cnt,
                        const float* __restrict__ fw3, const float* __restrict__ fb3,
                        float* __restrict__ allout) {
  int e = blockIdx.y;
  int count = cnt[e]; if (count > CAP) count = CAP;
  int rb = blockIdx.x * 16;
  if (rb >= count) return;
  __shared__ unsigned short rowbuf[16 * 256];
  __shared__ float wsh[256 * 12];
  int tid = threadIdx.x; // 256
  {
    int row = tid >> 4, c0 = (tid & 15) * 16;
    const unsigned short* src = f2buf + ((size_t)e * CAP + rb + row) * 256 + c0;
    *(uint4*)(&rowbuf[row * 256 + c0]) = *(const uint4*)(src);
    *(uint4*)(&rowbuf[row * 256 + c0 + 8]) = *(const uint4*)(src + 8);
  }
  for (int i = tid; i < 256 * 12; i += 256) wsh[i] = fw3[(size_t)e * 256 * 12 + i];
  __syncthreads();
  int r = tid >> 4, j = tid & 15;
  int slot = rb + r;
  if (j < 12 && slot < count) {
    float acc = fb3[e * 12 + j];
    for (int k = 0; k < 256; ++k)
      acc += b2f(rowbuf[r * 256 + k]) * wsh[k * 12 + j];
    int arow = perm[e * CAP + slot];
    allout[((size_t)arow * 8 + e) * 12 + j] = acc;
  }
}

// ------- mix: weighted sum of the two selected expert outputs -------
__global__ void k_mix(const float* __restrict__ selbuf, const float* __restrict__ allout,
                      float* __restrict__ out) {
  int b = blockIdx.x * 256 + threadIdx.x;
  int i0 = (int)selbuf[(size_t)b * 4 + 0];
  int i1 = (int)selbuf[(size_t)b * 4 + 1];
  float w0 = selbuf[(size_t)b * 4 + 2];
  float w1 = selbuf[(size_t)b * 4 + 3];
  const float* a0 = allout + ((size_t)b * 8 + i0) * 12;
  const float* a1 = allout + ((size_t)b * 8 + i1) * 12;
#pragma unroll
  for (int j = 0; j < 12; ++j)
    out[(size_t)b * 12 + j] = w0 * a0[j] + w1 * a1[j];
}

// ---------------- host ----------------

extern "C" void kernel_launch(void* const* d_in, const int* in_sizes, int n_in,
                              void* d_out, int out_size, void* d_ws, size_t ws_size,
                              hipStream_t stream) {
  const float* state = (const float*)d_in[0];
  const float* vlm   = (const float*)d_in[1];
  const float* sw1 = (const float*)d_in[2];  const float* sb1 = (const float*)d_in[3];
  const float* sg1 = (const float*)d_in[4];  const float* sh1 = (const float*)d_in[5];
  const float* sw2 = (const float*)d_in[6];  const float* sb2 = (const float*)d_in[7];
  const float* sg2 = (const float*)d_in[8];  const float* sh2 = (const float*)d_in[9];
  const float* vw1 = (const float*)d_in[10]; const float* vb1 = (const float*)d_in[11];
  const float* vg1 = (const float*)d_in[12]; const float* vh1 = (const float*)d_in[13];
  const float* vw2 = (const float*)d_in[14]; const float* vb2 = (const float*)d_in[15];
  const float* vg2 = (const float*)d_in[16]; const float* vh2 = (const float*)d_in[17];
  const float* fw1 = (const float*)d_in[18]; const float* fb1 = (const float*)d_in[19];
  const float* fg1 = (const float*)d_in[20]; const float* fh1 = (const float*)d_in[21];
  const float* fw2 = (const float*)d_in[22]; const float* fb2 = (const float*)d_in[23];
  const float* fg2 = (const float*)d_in[24]; const float* fh2 = (const float*)d_in[25];
  const float* fw3 = (const float*)d_in[26]; const float* fb3 = (const float*)d_in[27];
  const float* gw1 = (const float*)d_in[28]; const float* gb1 = (const float*)d_in[29];
  const float* gw2 = (const float*)d_in[30]; const float* gb2 = (const float*)d_in[31];
  const float* gw3 = (const float*)d_in[32]; const float* gb3 = (const float*)d_in[33];

  // ---- workspace layout with lifetime-based aliasing (~236 MB total) ----
  char* ws = (char*)d_ws;
  size_t off = 0;
  auto alloc = [&](size_t bytes) -> char* {
    char* p = ws + off;
    off = (off + bytes + 255) & ~(size_t)255;
    return p;
  };
  const size_t SZ_bufA = (size_t)NEXP * CAP * 512 * 2;  // 83.9 MB
  const size_t SZ_gh1  = (size_t)BROWS * 256 * 4;       // 33.6 MB
  const size_t SZ_gh2  = (size_t)BROWS * 128 * 4;       // 16.8 MB

  char* regA = alloc(SZ_bufA);
  unsigned short* bufA  = (unsigned short*)regA;              // h1v / f1b (expert phase)
  float* gh1            = (float*)regA;                       // gate phase only
  float* gh2            = (float*)(regA + SZ_gh1);            // gate phase only
  unsigned short* st_bf = (unsigned short*)(regA + SZ_gh1 + SZ_gh2); // dead after s1 (< v1)

  unsigned short* bufF = (unsigned short*)alloc((size_t)NEXP * CAP * 384 * 2); // 62.9 MB
  unsigned short* bufC = (unsigned short*)alloc((size_t)NEXP * CAP * 256 * 2); // 41.9 MB

  char* regV = alloc((size_t)BROWS * 512 * 2);                 // 33.6 MB
  unsigned short* vl_bf = (unsigned short*)regV;               // dead after v1
  float* allout         = (float*)regV;                        // written at out12 (after v1)

  float* selbuf = (float*)alloc((size_t)BROWS * 4 * 4);
  int*   perm   = (int*)alloc((size_t)NEXP * CAP * 4);
  int*   bcnt   = (int*)alloc(512 * 8 * 4);
  int*   bbase  = (int*)alloc(512 * 8 * 4);
  char*  cntaux = alloc(256);  // cnt: 8 ints at +0, aux: 8 floats at +64
  int*   cnt = (int*)cntaux;
  float* aux = (float*)(cntaux + 64);
  unsigned short* wt_s1 = (unsigned short*)alloc((size_t)8 * 256 * 128 * 2);
  unsigned short* wt_s2 = (unsigned short*)alloc((size_t)8 * 128 * 256 * 2);
  unsigned short* wt_v1 = (unsigned short*)alloc((size_t)8 * 512 * 512 * 2);
  unsigned short* wt_v2 = (unsigned short*)alloc((size_t)8 * 256 * 512 * 2);
  unsigned short* wt_f1 = (unsigned short*)alloc((size_t)8 * 512 * 384 * 2);
  unsigned short* wt_f2 = (unsigned short*)alloc((size_t)8 * 256 * 512 * 2);
  (void)ws_size; (void)in_sizes; (void)n_in; (void)out_size;

  float* outf = (float*)d_out;

  // prep
  k_convert_pad<<<(BROWS * 128 + 255) / 256, 256, 0, stream>>>(state, st_bf, BROWS, 96, 128);
  k_convert_pad<<<(BROWS * 512 + 255) / 256, 256, 0, stream>>>(vlm, vl_bf, BROWS, 512, 512);
  k_wtrans<<<dim3(4, 8, 8),   dim3(32, 8), 0, stream>>>(sw1, wt_s1, 96, 256, 128);
  k_wtrans<<<dim3(8, 4, 8),   dim3(32, 8), 0, stream>>>(sw2, wt_s2, 256, 128, 256);
  k_wtrans<<<dim3(16, 16, 8), dim3(32, 8), 0, stream>>>(vw1, wt_v1, 512, 512, 512);
  k_wtrans<<<dim3(16, 8, 8),  dim3(32, 8), 0, stream>>>(vw2, wt_v2, 512, 256, 512);
  k_wtrans<<<dim3(12, 16, 8), dim3(32, 8), 0, stream>>>(fw1, wt_f1, 384, 512, 384);
  k_wtrans<<<dim3(16, 8, 8),  dim3(32, 8), 0, stream>>>(fw2, wt_f2, 512, 256, 512);
  k_zero<<<1, 64, 0, stream>>>((int*)cntaux, 64);

  // gate (fp32 for exact top-k); gh1/gh2 live inside bufA region (pre-expert phase)
  k_gemm32<true><<<dim3(256, 2), 256, 0, stream>>>(state, 96, vlm, 512, 96,
                                                   gw1, gb1, 608, 256, gh1);
  k_gemm32<false><<<dim3(256, 1), 256, 0, stream>>>(gh1, 256, nullptr, 0, 0,
                                                    gw2, gb2, 256, 128, gh2);
  k_gatetop<<<BROWS / 256, 256, 0, stream>>>(gh2, gw3, gb3, outf, aux, bcnt, selbuf);
  k_scan<<<1, 64, 0, stream>>>(bcnt, bbase, cnt);
  k_fill<<<512, 64, 0, stream>>>(selbuf, bbase, perm);
  k_auxfinal<<<1, 64, 0, stream>>>(cnt, aux, outf);

  // experts: s-layers first (st_bf aliases bufA tail; must finish before v1 writes bufA)
  dim3 lg(CAPBLK, NEXP);
  k_layer<128, 256, true><<<lg, 512, 0, stream>>>(st_bf, 128, perm, cnt, wt_s1,
      sb1, sg1, sh1, bufC, 256, 0);
  k_layer<256, 128, false><<<lg, 512, 0, stream>>>(bufC, 256, perm, cnt, wt_s2,
      sb2, sg2, sh2, bufF, 384, 0);
  k_layer<512, 512, true><<<lg, 512, 0, stream>>>(vl_bf, 512, perm, cnt, wt_v1,
      vb1, vg1, vh1, bufA, 512, 0);
  k_layer<512, 256, false><<<lg, 512, 0, stream>>>(bufA, 512, perm, cnt, wt_v2,
      vb2, vg2, vh2, bufF, 384, 128);
  k_layer<384, 512, false><<<lg, 512, 0, stream>>>(bufF, 384, perm, cnt, wt_f1,
      fb1, fg1, fh1, bufA, 512, 0);
  k_layer<512, 256, false><<<lg, 512, 0, stream>>>(bufA, 512, perm, cnt, wt_f2,
      fb2, fg2, fh2, bufC, 256, 0);
  k_out12<<<dim3(CAP / 16, NEXP), 256, 0, stream>>>(bufC, perm, cnt, fw3, fb3, allout);

  k_mix<<<BROWS / 256, 256, 0, stream>>>(selbuf, allout, outf);
}